// Round 5
// baseline (1260.567 us; speedup 1.0000x reference)
//
#include <hip/hip_runtime.h>
#include <hip/hip_bf16.h>
#include <stdint.h>

// ---------------------------------------------------------------------------
// UVSeamGNN R11: 2D-bucketed edge order for L2-resident gathers.
// R10 post-mortem: scheduling fixes (prefetch coverage R9, barrier-free TLP
// R10) both null at ~150us, VALU 47 / Mfma 7. Little's law on the 2.5TB/s
// beyond-L2 stream at ~700-1000cy L3 latency => only ~64 in-flight 64B lines
// per CU: the kernel is VMEM-request-queue bound; software depth can't raise
// it. Lever: cut per-request LATENCY by making gathers L2-resident.
// rec[] is now sorted by key=(dst/12500)*64 + src/1563 (8 dst-stripes x 64
// src-blocks); edge kernel pins dst-stripe = blockIdx%8 (XCD heuristic):
//   Pd window 3.2MB resident in the XCD's 4MB L2 for the whole sweep;
//   Ps windows 0.4MB stream through L2 bucket by bucket.
// Math is order-agnostic (records carry src/dst/eid/attr; out[eid] scatter);
// boundary tiles double-processed idempotently. CSR for agg kernels kept.
// Workspace (4B words), N=100000, E=1600000:
//   rowptr @0        [N+1]
//   cursor @100004   [N]
//   partial@200004   [512]
//   src4   @200516   [E]      (src per CSR slot, for agg kernels)
//   rec    @1800520  [E*4]    (uint4, 2D-bucket order)
//   mean1  @8200520  [N*6]
//   cat2b  @8800520  [N*256]b (cols 0..127: h1/Ps; 128..255: mean2/Pd+b1)
//   h2b    @21600520 [N*128]b
//   B2f    @28000520 [32768]u16   WSDf @28016904 [32768]u16
//   W2f    @28033288 [8192]u16    pbias@28037384 [256]f32
//   bhist  @28037640 [512]  bptr @28038152 [513]  bcur @28038668 [512]
// total ~112.16 MB
// ---------------------------------------------------------------------------

typedef unsigned short u16;
typedef short bf16x8 __attribute__((ext_vector_type(8)));
typedef float f32x4 __attribute__((ext_vector_type(4)));
typedef float f32x2 __attribute__((ext_vector_type(2)));

#define NMASK 0x1FFFF
#define DDIV 12500
#define SDIV 1563

__device__ __forceinline__ u16 f2b(float f) {
  unsigned u = __builtin_bit_cast(unsigned, f);
  u = u + 0x7fffu + ((u >> 16) & 1u);
  return (u16)(u >> 16);
}
__device__ __forceinline__ float bflo(unsigned u) {
  return __builtin_bit_cast(float, u << 16);
}
__device__ __forceinline__ float bfhi(unsigned u) {
  return __builtin_bit_cast(float, u & 0xffff0000u);
}
__device__ __forceinline__ f32x2 unpk2(unsigned u) {
  return (f32x2){bflo(u), bfhi(u)};
}
__device__ __forceinline__ unsigned pack2bf(float a, float b) {
  unsigned ua = __builtin_bit_cast(unsigned, a);
  unsigned ub = __builtin_bit_cast(unsigned, b);
  ua = ua + 0x7fffu + ((ua >> 16) & 1u);
  ub = ub + 0x7fffu + ((ub >> 16) & 1u);
  return (ua >> 16) | (ub & 0xffff0000u);
}
__device__ __forceinline__ unsigned packrn(f32x2 f) {
  __hip_bfloat162 h = __float22bfloat162_rn(make_float2(f.x, f.y));
  unsigned r;
  __builtin_memcpy(&r, &h, 4);
  return r;
}

// ---- CSR build (by dst, for agg kernels) ----
__global__ void hist_kernel(const int* __restrict__ ei, int* __restrict__ cnt,
                            int E) {
  int e = blockIdx.x * blockDim.x + threadIdx.x;
  if (e < E) atomicAdd(&cnt[ei[E + e]], 1);
}

__global__ void scan_block_sums(const int* __restrict__ cnt,
                                int* __restrict__ partial, int N) {
  __shared__ int red[256];
  int t = threadIdx.x;
  int n = blockIdx.x * 256 + t;
  red[t] = (n < N) ? cnt[n] : 0;
  __syncthreads();
  for (int off = 128; off; off >>= 1) {
    if (t < off) red[t] += red[t + off];
    __syncthreads();
  }
  if (t == 0) partial[blockIdx.x] = red[0];
}

__global__ void scan_partials(int* __restrict__ partial,
                              int* __restrict__ rowptr, int NBLK, int E,
                              int N) {
  __shared__ int sc[512];
  int t = threadIdx.x;
  int v = (t < NBLK) ? partial[t] : 0;
  sc[t] = v;
  __syncthreads();
  for (int off = 1; off < 512; off <<= 1) {
    int a = (t >= off) ? sc[t - off] : 0;
    __syncthreads();
    sc[t] += a;
    __syncthreads();
  }
  if (t < NBLK) partial[t] = sc[t] - v;  // exclusive
  if (t == 0) rowptr[N] = E;
}

__global__ void scan_final(const int* __restrict__ partial,
                           int* __restrict__ cursor, int* __restrict__ rowptr,
                           int N) {
  __shared__ int sc[256];
  int t = threadIdx.x;
  int n = blockIdx.x * 256 + t;
  int v = (n < N) ? cursor[n] : 0;
  sc[t] = v;
  __syncthreads();
  for (int off = 1; off < 256; off <<= 1) {
    int a = (t >= off) ? sc[t - off] : 0;
    __syncthreads();
    sc[t] += a;
    __syncthreads();
  }
  int excl = partial[blockIdx.x] + sc[t] - v;
  if (n < N) {
    rowptr[n] = excl;
    cursor[n] = excl;
  }
}

// scatter src-only array (CSR order, for agg kernels)
__global__ void scatter_src(const int* __restrict__ ei,
                            int* __restrict__ cursor,
                            unsigned* __restrict__ src4, int E) {
  int e = blockIdx.x * blockDim.x + threadIdx.x;
  if (e >= E) return;
  int s = ei[e];
  int d = ei[E + e];
  int pos = atomicAdd(&cursor[d], 1);
  src4[pos] = (unsigned)s;
}

// ---- 2D bucket build: key = (dst/12500)*64 + src/1563 ----
__global__ void bucket_hist(const int* __restrict__ ei, int* __restrict__ bhist,
                            int E) {
  __shared__ int h[512];
  int t = threadIdx.x;
  h[t] = 0;
  h[t + 256] = 0;
  __syncthreads();
  int e = blockIdx.x * blockDim.x + t;
  if (e < E) {
    int s = ei[e];
    int d = ei[E + e];
    int key = (d / DDIV) * 64 + s / SDIV;
    atomicAdd(&h[key], 1);
  }
  __syncthreads();
  if (h[t]) atomicAdd(&bhist[t], h[t]);
  if (h[t + 256]) atomicAdd(&bhist[t + 256], h[t + 256]);
}

__global__ void bucket_scan(const int* __restrict__ bhist,
                            int* __restrict__ bptr, int* __restrict__ bcur,
                            int E) {
  __shared__ int sc[512];
  int t = threadIdx.x;
  int v = bhist[t];
  sc[t] = v;
  __syncthreads();
  for (int off = 1; off < 512; off <<= 1) {
    int a = (t >= off) ? sc[t - off] : 0;
    __syncthreads();
    sc[t] += a;
    __syncthreads();
  }
  int excl = sc[t] - v;
  bptr[t] = excl;
  bcur[t] = excl;
  if (t == 0) bptr[512] = E;
}

// scatter packed 16B record in 2D-bucket order
__global__ void scatter2_rec(const int* __restrict__ ei,
                             const float* __restrict__ attr,
                             int* __restrict__ bcur, uint4* __restrict__ rec,
                             int E) {
  int e = blockIdx.x * blockDim.x + threadIdx.x;
  if (e >= E) return;
  int s = ei[e];
  int d = ei[E + e];
  float4 a4 = *(const float4*)(attr + (size_t)e * 4);
  int key = (d / DDIV) * 64 + s / SDIV;
  int pos = atomicAdd(&bcur[key], 1);
  uint4 r;
  r.x = (unsigned)s | ((unsigned)(d & 0x7FFF) << 17);
  r.y = ((unsigned)d >> 15) | ((unsigned)e << 2);
  r.z = pack2bf(a4.x, a4.y);
  r.w = pack2bf(a4.z, a4.w);
  rec[pos] = r;
}

// ---- pack weights into bf16 MFMA B-fragment layouts ----
__global__ void pack_weights(const float* __restrict__ w2_root,
                             const float* __restrict__ w2_neigh,
                             const float* __restrict__ w_e1,
                             const float* __restrict__ w_e2,
                             const float* __restrict__ b_e1,
                             u16* __restrict__ B2f, u16* __restrict__ WSDf,
                             u16* __restrict__ W2f, float* __restrict__ pbias) {
  int t = blockIdx.x * 256 + threadIdx.x;
  if (t < 32768) {  // B2f: KT=8, NT=8 over [w2_root; w2_neigh] (K=256, N=128)
    int j = t & 7, lane = (t >> 3) & 63, nt = (t >> 9) & 7, kt = t >> 12;
    int k = kt * 32 + (lane >> 4) * 8 + j;
    int n = nt * 16 + (lane & 15);
    float v = (k < 128) ? w2_root[k * 128 + n] : w2_neigh[(k - 128) * 128 + n];
    B2f[t] = f2b(v);
  } else if (t < 65536) {  // WSDf: KT=4, NT=16 over [Ws | Wd] (K=128, N=256)
    int t2 = t - 32768;
    int j = t2 & 7, lane = (t2 >> 3) & 63, nt = (t2 >> 9) & 15, kt = t2 >> 13;
    int k = kt * 32 + (lane >> 4) * 8 + j;
    int n = nt * 16 + (lane & 15);
    float v = (n < 128) ? w_e1[k * 128 + n] : w_e1[(128 + k) * 128 + (n - 128)];
    WSDf[t2] = f2b(v);
  } else if (t < 73728) {  // W2f: KT=4, NT=4 over w_e2 (K=128, N=64)
    int t2 = t - 65536;
    int j = t2 & 7, lane = (t2 >> 3) & 63, nt = (t2 >> 9) & 3, kt = t2 >> 11;
    int k = kt * 32 + (lane >> 4) * 8 + j;
    int n = nt * 16 + (lane & 15);
    W2f[t2] = f2b(w_e2[k * 64 + n]);
  } else if (t < 73984) {  // pbias
    int n = t - 73728;
    pbias[n] = (n < 128) ? 0.0f : b_e1[n - 128];
  }
}

// ---- layer-1 mean aggregation: wave/node, 8 rows x 8 lanes, 4-deep ----
__global__ __launch_bounds__(256) void agg1_kernel(
    const float* __restrict__ x, const int* __restrict__ rowptr,
    const unsigned* __restrict__ src4, float* __restrict__ mean1, int N) {
  int n = blockIdx.x * 4 + (threadIdx.x >> 6);
  if (n >= N) return;
  int lane = threadIdx.x & 63;
  int g = lane >> 3;  // row group 0..7
  int c = lane & 7;   // col 0..7 (0..5 valid)
  int beg = rowptr[n], end = rowptr[n + 1];
  float a = 0.0f;
  if (c < 6) {
    int idx[4];
#pragma unroll
    for (int j = 0; j < 4; j++) {
      int ii = beg + g + j * 8;
      idx[j] = (ii < end) ? (int)src4[ii] : -1;
    }
    float v[4];
#pragma unroll
    for (int j = 0; j < 4; j++)
      v[j] = x[(size_t)(idx[j] < 0 ? 0 : idx[j]) * 6 + c];
#pragma unroll
    for (int j = 0; j < 4; j++)
      if (idx[j] >= 0) a += v[j];
    for (int ii = beg + g + 32; ii < end; ii += 8) {
      a += x[(size_t)src4[ii] * 6 + c];
    }
  }
  a += __shfl_xor(a, 8, 64);
  a += __shfl_xor(a, 16, 64);
  a += __shfl_xor(a, 32, 64);
  if (g == 0 && c < 6)
    mean1[(size_t)n * 6 + c] = a / (float)max(end - beg, 1);
}

// ---- dense layer 1 -> h1 bf16 into cat2b cols 0..127, LDS-staged ----
__global__ __launch_bounds__(256) void dense1_kernel(
    const float* __restrict__ x, const float* __restrict__ mean1,
    const float* __restrict__ w_root, const float* __restrict__ w_neigh,
    const float* __restrict__ b, u16* __restrict__ cat2b, int N) {
  __shared__ float sxm[384];  // [0:192) x for 32 nodes, [192:384) mean1
  int t = threadIdx.x;
  int col = t & 127;
  int half = t >> 7;
  float wr[6], wn[6];
#pragma unroll
  for (int j = 0; j < 6; j++) {
    wr[j] = w_root[j * 128 + col];
    wn[j] = w_neigh[j * 128 + col];
  }
  float bb = b[col];
  for (int base = blockIdx.x * 32; base < N; base += gridDim.x * 32) {
    int cnt = min(32, N - base) * 6;
    __syncthreads();
    for (int i = t; i < 384; i += 256) {
      if (i < 192)
        sxm[i] = (i < cnt) ? x[(size_t)base * 6 + i] : 0.0f;
      else
        sxm[i] = (i - 192 < cnt) ? mean1[(size_t)base * 6 + (i - 192)] : 0.0f;
    }
    __syncthreads();
#pragma unroll
    for (int sub = 0; sub < 16; sub++) {
      int nl = sub * 2 + half;
      int n = base + nl;
      if (n < N) {
        float s = bb;
#pragma unroll
        for (int j = 0; j < 6; j++)
          s += sxm[nl * 6 + j] * wr[j] + sxm[192 + nl * 6 + j] * wn[j];
        cat2b[(size_t)n * 256 + col] = f2b(fmaxf(s, 0.0f));
      }
    }
  }
}

// ---- layer-2 mean aggregation: wave/node, 4x16 lanes, 8-deep prefetch ----
__global__ __launch_bounds__(256) void agg2_kernel(
    const u16* __restrict__ cat2b, u16* __restrict__ cat2w,
    const int* __restrict__ rowptr, const unsigned* __restrict__ src4, int N) {
  int n = blockIdx.x * 4 + (threadIdx.x >> 6);
  if (n >= N) return;
  int lane = threadIdx.x & 63;
  int g = lane >> 4;  // row group 0..3
  int c = lane & 15;  // col chunk (8 bf16)
  int beg = rowptr[n], end = rowptr[n + 1];
  f32x2 acc2[4];
#pragma unroll
  for (int j = 0; j < 4; j++) acc2[j] = (f32x2){0.f, 0.f};

  const int DEPTH = 8;
  int idx[DEPTH];
#pragma unroll
  for (int j = 0; j < DEPTH; j++) {
    int ii = beg + g + j * 4;
    idx[j] = (ii < end) ? (int)src4[ii] : -1;
  }
  uint4 u[DEPTH];
#pragma unroll
  for (int j = 0; j < DEPTH; j++) {
    int s = idx[j] < 0 ? 0 : idx[j];
    u[j] = *(const uint4*)(cat2b + (size_t)s * 256 + c * 8);
  }
#pragma unroll
  for (int j = 0; j < DEPTH; j++) {
    if (idx[j] >= 0) {
      acc2[0] += unpk2(u[j].x);
      acc2[1] += unpk2(u[j].y);
      acc2[2] += unpk2(u[j].z);
      acc2[3] += unpk2(u[j].w);
    }
  }
  for (int ii = beg + g + DEPTH * 4; ii < end; ii += 4) {
    uint4 uu = *(const uint4*)(cat2b + (size_t)src4[ii] * 256 + c * 8);
    acc2[0] += unpk2(uu.x);
    acc2[1] += unpk2(uu.y);
    acc2[2] += unpk2(uu.z);
    acc2[3] += unpk2(uu.w);
  }
#pragma unroll
  for (int j = 0; j < 4; j++) {
    acc2[j].x += __shfl_xor(acc2[j].x, 16, 64);
    acc2[j].y += __shfl_xor(acc2[j].y, 16, 64);
    acc2[j].x += __shfl_xor(acc2[j].x, 32, 64);
    acc2[j].y += __shfl_xor(acc2[j].y, 32, 64);
  }
  if (g == 0) {
    float inv = 1.0f / (float)max(end - beg, 1);
    uint4 ov;
    ov.x = packrn(acc2[0] * inv);
    ov.y = packrn(acc2[1] * inv);
    ov.z = packrn(acc2[2] * inv);
    ov.w = packrn(acc2[3] * inv);
    *(uint4*)(cat2w + (size_t)n * 256 + 128 + c * 8) = ov;
  }
}

// ---- bf16 MFMA GEMM: 512 thr, 8 waves, M-tile 128 ----
template <int KT, int NT, bool RELU>
__global__ __launch_bounds__(512) void mfma_gemm(
    const u16* __restrict__ A, int lda, const u16* __restrict__ Bf,
    const float* __restrict__ bias, u16* __restrict__ C, int ldc, int M) {
  __shared__ u16 sB[KT * NT * 512];
  int tid = threadIdx.x;
  for (int i = tid; i < KT * NT * 64; i += 512)
    ((uint4*)sB)[i] = ((const uint4*)Bf)[i];
  int w = tid >> 6, l = tid & 63;
  int quad = l >> 4, col16 = l & 15;
  int rowA = blockIdx.x * 128 + w * 16 + col16;
  bool rv = rowA < M;
  const u16* ap = A + (size_t)rowA * lda + quad * 8;
  f32x4 acc[NT];
#pragma unroll
  for (int nt = 0; nt < NT; nt++) acc[nt] = (f32x4){0.f, 0.f, 0.f, 0.f};
  __syncthreads();
#pragma unroll
  for (int kt = 0; kt < KT; kt++) {
    bf16x8 av = {};
    if (rv) av = *(const bf16x8*)(ap + kt * 32);
#pragma unroll
    for (int nt = 0; nt < NT; nt++) {
      bf16x8 bv = *(const bf16x8*)(sB + ((kt * NT + nt) * 64 + l) * 8);
      acc[nt] = __builtin_amdgcn_mfma_f32_16x16x32_bf16(av, bv, acc[nt], 0, 0, 0);
    }
  }
  int rowbase = blockIdx.x * 128 + w * 16 + quad * 4;
#pragma unroll
  for (int r = 0; r < 4; r++) {
    int row = rowbase + r;
    if (row < M) {
#pragma unroll
      for (int nt = 0; nt < NT; nt++) {
        float v = acc[nt][r] + bias[nt * 16 + col16];
        if (RELU) v = fmaxf(v, 0.0f);
        C[(size_t)row * ldc + nt * 16 + col16] = f2b(v);
      }
    }
  }
}

// ---- barrier-free wave-local edge MLP over dst-stripe (XCD-pinned) ----
__global__ __launch_bounds__(256) void edge_mfma_kernel(
    const u16* __restrict__ Pcatb, const uint4* __restrict__ rec,
    const u16* __restrict__ W2f, const float* __restrict__ b_e2,
    const float* __restrict__ w_e3, const float* __restrict__ b_e3,
    const float* __restrict__ w_e1, const int* __restrict__ bptr,
    float* __restrict__ out, int E) {
  __shared__ u16 sV[64 * 136];  // 4 wave-private slices [16][136]
  __shared__ u16 sW2[8192];

  int tid = threadIdx.x;
  int w = tid >> 6, l = tid & 63, quad = l >> 4, c16 = l & 15;
  int eg = l >> 4, ac = l & 15;  // wave-local phase-A mapping
  u16* sVw = sV + w * 16 * 136;

  for (int i = tid; i < 1024; i += 256)
    ((uint4*)sW2)[i] = ((const uint4*)W2f)[i];
  __syncthreads();  // only barrier: sW2 ready; loop below is barrier-free

  // wa2[j][p2]: rows j=0..3 of Wa, column pair p2 for this thread's 8 cols
  f32x2 wa2[4][4];
#pragma unroll
  for (int j = 0; j < 4; j++) {
    float4 w0 = *(const float4*)(w_e1 + (256 + j) * 128 + ac * 8);
    float4 w1 = *(const float4*)(w_e1 + (256 + j) * 128 + ac * 8 + 4);
    wa2[j][0] = (f32x2){w0.x, w0.y};
    wa2[j][1] = (f32x2){w0.z, w0.w};
    wa2[j][2] = (f32x2){w1.x, w1.y};
    wa2[j][3] = (f32x2){w1.z, w1.w};
  }
  float w3v[4], be2[4];
#pragma unroll
  for (int nt = 0; nt < 4; nt++) {
    w3v[nt] = w_e3[nt * 16 + c16];
    be2[nt] = b_e2[nt * 16 + c16];
  }
  float b3 = b_e3[0];

  // dst-stripe = blockIdx%8 (XCD round-robin heuristic; perf-only).
  // Stripe s covers rec slots [bptr[s*64], bptr[(s+1)*64]) -> 16-edge tiles
  // [tb, te); boundary tiles double-processed (idempotent out[eid] writes).
  int s8 = blockIdx.x & 7;
  int tb = bptr[s8 * 64] >> 4;
  int te = (bptr[(s8 + 1) * 64] + 15) >> 4;
  int wi = (blockIdx.x >> 3) * 4 + w;  // wave index within stripe: 0..511
  const int NW = 512;                  // wave-stream stride within stripe
  int t = tb + wi;

  uint4 rcA[4], rcB[4];  // rec double buffer (sequential, 2 tiles deep)
  uint4 ps[4];           // rolling ps buffer: refilled for t+NW during phase A

  auto load_rec = [&](int tt, uint4* rcv) {
#pragma unroll
    for (int it = 0; it < 4; it++) {
      int e = min(tt * 16 + it * 4 + eg, E - 1);
      rcv[it] = rec[e];
    }
  };

  // process wave-tile t: cur = rec(t), nxt = rec(t+NW); on exit cur = rec(t+2NW)
  auto process = [&](int t, uint4* cur, uint4* nxt) {
    bool hasnext = (t + NW < te);
    // pd block FIRST (oldest in vmcnt FIFO): stripe rows L2-resident
    uint4 pdv[4];
#pragma unroll
    for (int it = 0; it < 4; it++) {
      int d = (int)(((cur[it].x >> 17) | (cur[it].y << 15)) & NMASK);
      pdv[it] = *(const uint4*)(Pcatb + (size_t)d * 256 + 128 + ac * 8);
    }
    // phase A: consume ps[it]/pdv[it], then refill ps[it] for tile t+NW
#pragma unroll
    for (int it = 0; it < 4; it++) {
      int e = it * 4 + eg;  // 0..15 local edge
      uint4 psu = ps[it], pdu = pdv[it];
      f32x2 a01 = unpk2(cur[it].z);
      f32x2 a23 = unpk2(cur[it].w);
      unsigned pu[4] = {psu.x, psu.y, psu.z, psu.w};
      unsigned du[4] = {pdu.x, pdu.y, pdu.z, pdu.w};
      uint4 ov;
      unsigned* op = (unsigned*)&ov;
#pragma unroll
      for (int p2 = 0; p2 < 4; p2++) {
        f32x2 f = unpk2(pu[p2]) + unpk2(du[p2]);
        f += a01.x * wa2[0][p2];
        f += a01.y * wa2[1][p2];
        f += a23.x * wa2[2][p2];
        f += a23.y * wa2[3][p2];
        f = __builtin_elementwise_max(f, (f32x2){0.f, 0.f});
        op[p2] = packrn(f);
      }
      *(uint4*)(sVw + e * 136 + ac * 8) = ov;
      if (ac == 0) *(unsigned*)(sVw + e * 136 + 128) = cur[it].y >> 2;
      if (hasnext) {
        int s = (int)(nxt[it].x & NMASK);
        ps[it] = *(const uint4*)(Pcatb + (size_t)s * 256 + ac * 8);
      }
    }
    // cur fully consumed -> reuse as rec(t+2NW) prefetch target
    if (t + 2 * NW < te) load_rec(t + 2 * NW, cur);
    // phase B: MFMA from own sV slice + relu/w3 reduce + scatter out
    f32x4 acc[4];
#pragma unroll
    for (int nt = 0; nt < 4; nt++) acc[nt] = (f32x4){0.f, 0.f, 0.f, 0.f};
    const u16* vp = sVw + c16 * 136 + quad * 8;
#pragma unroll
    for (int kt = 0; kt < 4; kt++) {
      bf16x8 av = *(const bf16x8*)(vp + kt * 32);
#pragma unroll
      for (int nt = 0; nt < 4; nt++) {
        bf16x8 bv = *(const bf16x8*)(sW2 + ((kt * 4 + nt) * 64 + l) * 8);
        acc[nt] =
            __builtin_amdgcn_mfma_f32_16x16x32_bf16(av, bv, acc[nt], 0, 0, 0);
      }
    }
#pragma unroll
    for (int r = 0; r < 4; r++) {
      float p = 0.0f;
#pragma unroll
      for (int nt = 0; nt < 4; nt++)
        p += fmaxf(acc[nt][r] + be2[nt], 0.0f) * w3v[nt];
      p += __shfl_xor(p, 1, 64);
      p += __shfl_xor(p, 2, 64);
      p += __shfl_xor(p, 4, 64);
      p += __shfl_xor(p, 8, 64);
      if (c16 == 0) {
        int eloc = quad * 4 + r;  // 0..15 local edge
        if (t * 16 + eloc < E) {
          unsigned eid = *(const unsigned*)(sVw + eloc * 136 + 128);
          out[eid] = p + b3;
        }
      }
    }
  };

  if (t >= te) return;
  // prologue: rec 2-deep, ps for first tile (full latency once)
  load_rec(t, rcA);
#pragma unroll
  for (int it = 0; it < 4; it++) {
    int s = (int)(rcA[it].x & NMASK);
    ps[it] = *(const uint4*)(Pcatb + (size_t)s * 256 + ac * 8);
  }
  if (t + NW < te) load_rec(t + NW, rcB);

  while (t < te) {
    process(t, rcA, rcB);  // consumes ps(t), refills ps from rcB, rcA<-rec(t+2NW)
    t += NW;
    if (t >= te) break;
    process(t, rcB, rcA);
    t += NW;
  }
}

extern "C" void kernel_launch(void* const* d_in, const int* in_sizes, int n_in,
                              void* d_out, int out_size, void* d_ws,
                              size_t ws_size, hipStream_t stream) {
  const float* x        = (const float*)d_in[0];
  const int*   ei       = (const int*)d_in[1];
  const float* attr     = (const float*)d_in[2];
  const float* w1_root  = (const float*)d_in[3];
  const float* w1_neigh = (const float*)d_in[4];
  const float* b1       = (const float*)d_in[5];
  const float* w2_root  = (const float*)d_in[6];
  const float* w2_neigh = (const float*)d_in[7];
  const float* b2       = (const float*)d_in[8];
  const float* w_e1     = (const float*)d_in[9];
  const float* b_e1     = (const float*)d_in[10];
  const float* w_e2     = (const float*)d_in[11];
  const float* b_e2     = (const float*)d_in[12];
  const float* w_e3     = (const float*)d_in[13];
  const float* b_e3     = (const float*)d_in[14];
  float* out = (float*)d_out;

  int N = in_sizes[0] / 6;
  int E = in_sizes[2] / 4;
  int NBLK = (N + 255) / 256;

  int* wsi = (int*)d_ws;
  int*      rowptr  = wsi;                         // [N+1]
  int*      cursor  = wsi + 100004;                // [N]
  int*      partial = wsi + 200004;                // [512]
  unsigned* src4    = (unsigned*)(wsi + 200516);   // [E]
  uint4*    rec     = (uint4*)(wsi + 1800520);     // [E] x 16B (bucket order)
  float*    mean1   = (float*)(wsi + 8200520);     // [N,6]
  u16*      cat2b   = (u16*)(wsi + 8800520);       // [N,256] bf16
  u16*      h2b     = (u16*)(wsi + 21600520);      // [N,128] bf16
  u16*      B2f     = (u16*)(wsi + 28000520);      // 32768 u16
  u16*      WSDf    = (u16*)(wsi + 28016904);      // 32768 u16
  u16*      W2f     = (u16*)(wsi + 28033288);      // 8192 u16
  float*    pbias   = (float*)(wsi + 28037384);    // 256 f32
  int*      bhist   = wsi + 28037640;              // [512]
  int*      bptr    = wsi + 28038152;              // [513]
  int*      bcur    = wsi + 28038668;              // [512]

  (void)hipMemsetAsync(cursor, 0, (size_t)N * sizeof(int), stream);
  (void)hipMemsetAsync(bhist, 0, 512 * sizeof(int), stream);

  pack_weights<<<289, 256, 0, stream>>>(w2_root, w2_neigh, w_e1, w_e2, b_e1,
                                        B2f, WSDf, W2f, pbias);

  // CSR build (by dst) for agg kernels
  hist_kernel<<<(E + 255) / 256, 256, 0, stream>>>(ei, cursor, E);
  scan_block_sums<<<NBLK, 256, 0, stream>>>(cursor, partial, N);
  scan_partials<<<1, 512, 0, stream>>>(partial, rowptr, NBLK, E, N);
  scan_final<<<NBLK, 256, 0, stream>>>(partial, cursor, rowptr, N);
  scatter_src<<<(E + 255) / 256, 256, 0, stream>>>(ei, cursor, src4, E);

  // 2D bucket build (8 dst-stripes x 64 src-blocks) for edge kernel
  bucket_hist<<<(E + 255) / 256, 256, 0, stream>>>(ei, bhist, E);
  bucket_scan<<<1, 512, 0, stream>>>(bhist, bptr, bcur, E);
  scatter2_rec<<<(E + 255) / 256, 256, 0, stream>>>(ei, attr, bcur, rec, E);

  // layer 1
  agg1_kernel<<<(N + 3) / 4, 256, 0, stream>>>(x, rowptr, src4, mean1, N);
  dense1_kernel<<<1024, 256, 0, stream>>>(x, mean1, w1_root, w1_neigh, b1,
                                          cat2b, N);

  // layer 2 aggregation (8-deep pipelined bf16 gather)
  agg2_kernel<<<(N + 3) / 4, 256, 0, stream>>>(cat2b, cat2b, rowptr, src4, N);

  int gblocks = (N + 127) / 128;
  // h2 = relu([h1|mean2] @ [w2_root;w2_neigh] + b2)
  mfma_gemm<8, 8, true><<<gblocks, 512, 0, stream>>>(cat2b, 256, B2f, b2, h2b,
                                                     128, N);
  // Pcat = h2 @ [Ws|Wd] + [0|b_e1]
  mfma_gemm<4, 16, false><<<gblocks, 512, 0, stream>>>(h2b, 128, WSDf, pbias,
                                                       cat2b, 256, N);

  // stripe-local fused edge MLP (L2-resident gathers)
  edge_mfma_kernel<<<1024, 256, 0, stream>>>(cat2b, rec, W2f, b_e2, w_e3,
                                             b_e3, w_e1, bptr, out, E);
}

// Round 6
// 780.823 us; speedup vs baseline: 1.6144x; 1.6144x over previous
//
#include <hip/hip_runtime.h>
#include <hip/hip_bf16.h>
#include <stdint.h>

// ---------------------------------------------------------------------------
// UVSeamGNN R12: R11's 2D-bucketed edge order, with the bucket build replaced
// by a contention-free counting sort. R11 post-mortem: scatter2_rec was 478us
// (VALU 0.3%) -- 1.6M global atomicAdd-with-return over 512 contiguous
// counters = 32 cache lines -> L2-bank serialization; bucket_hist had the
// same issue. Edge kernel's bucketed time was invisible (top-5 all scatter).
// R12 build: (1) bucket_hist2: 4096 edges/block -> LDS hist -> per-block row
// gh[blk][512] (coalesced stores, NO global atomics); (2) bucket_scan2:
// 1 block, thread k owns bucket k, walks blocks (coalesced across k) making
// per-(block,bucket) bases, 512-scan for bptr, fold in; (3) scatter2_rec:
// re-read edges, LDS-only rank atomics, direct 16B store. gh lives in h2b's
// slot (lifetimes disjoint: bucket build ends before gemm1 writes h2b).
// Edge kernel/CSR/aggs/GEMMs unchanged from R11. Next profile must show
// edge_mfma -> adjudicates the bucketing theory (keep if <=120us, revert if
// >=140us).
// Workspace (4B words), N=100000, E=1600000:
//   rowptr @0        [N+1]
//   cursor @100004   [N]
//   partial@200004   [512]
//   src4   @200516   [E]      (src per CSR slot, for agg kernels)
//   rec    @1800520  [E*4]    (uint4, 2D-bucket order)
//   mean1  @8200520  [N*6]
//   cat2b  @8800520  [N*256]b (cols 0..127: h1/Ps; 128..255: mean2/Pd+b1)
//   h2b    @21600520 [N*128]b  (also hosts gh[391*512] during bucket build)
//   B2f    @28000520 [32768]u16   WSDf @28016904 [32768]u16
//   W2f    @28033288 [8192]u16    pbias@28037384 [256]f32
//   bptr   @28037640 [513]
// total ~112.15 MB
// ---------------------------------------------------------------------------

typedef unsigned short u16;
typedef short bf16x8 __attribute__((ext_vector_type(8)));
typedef float f32x4 __attribute__((ext_vector_type(4)));
typedef float f32x2 __attribute__((ext_vector_type(2)));

#define NMASK 0x1FFFF
#define DDIV 12500
#define SDIV 1563
#define EPB 4096  // edges per block in bucket build

__device__ __forceinline__ u16 f2b(float f) {
  unsigned u = __builtin_bit_cast(unsigned, f);
  u = u + 0x7fffu + ((u >> 16) & 1u);
  return (u16)(u >> 16);
}
__device__ __forceinline__ float bflo(unsigned u) {
  return __builtin_bit_cast(float, u << 16);
}
__device__ __forceinline__ float bfhi(unsigned u) {
  return __builtin_bit_cast(float, u & 0xffff0000u);
}
__device__ __forceinline__ f32x2 unpk2(unsigned u) {
  return (f32x2){bflo(u), bfhi(u)};
}
__device__ __forceinline__ unsigned pack2bf(float a, float b) {
  unsigned ua = __builtin_bit_cast(unsigned, a);
  unsigned ub = __builtin_bit_cast(unsigned, b);
  ua = ua + 0x7fffu + ((ua >> 16) & 1u);
  ub = ub + 0x7fffu + ((ub >> 16) & 1u);
  return (ua >> 16) | (ub & 0xffff0000u);
}
__device__ __forceinline__ unsigned packrn(f32x2 f) {
  __hip_bfloat162 h = __float22bfloat162_rn(make_float2(f.x, f.y));
  unsigned r;
  __builtin_memcpy(&r, &h, 4);
  return r;
}

// ---- CSR build (by dst, for agg kernels) ----
__global__ void hist_kernel(const int* __restrict__ ei, int* __restrict__ cnt,
                            int E) {
  int e = blockIdx.x * blockDim.x + threadIdx.x;
  if (e < E) atomicAdd(&cnt[ei[E + e]], 1);
}

__global__ void scan_block_sums(const int* __restrict__ cnt,
                                int* __restrict__ partial, int N) {
  __shared__ int red[256];
  int t = threadIdx.x;
  int n = blockIdx.x * 256 + t;
  red[t] = (n < N) ? cnt[n] : 0;
  __syncthreads();
  for (int off = 128; off; off >>= 1) {
    if (t < off) red[t] += red[t + off];
    __syncthreads();
  }
  if (t == 0) partial[blockIdx.x] = red[0];
}

__global__ void scan_partials(int* __restrict__ partial,
                              int* __restrict__ rowptr, int NBLK, int E,
                              int N) {
  __shared__ int sc[512];
  int t = threadIdx.x;
  int v = (t < NBLK) ? partial[t] : 0;
  sc[t] = v;
  __syncthreads();
  for (int off = 1; off < 512; off <<= 1) {
    int a = (t >= off) ? sc[t - off] : 0;
    __syncthreads();
    sc[t] += a;
    __syncthreads();
  }
  if (t < NBLK) partial[t] = sc[t] - v;  // exclusive
  if (t == 0) rowptr[N] = E;
}

__global__ void scan_final(const int* __restrict__ partial,
                           int* __restrict__ cursor, int* __restrict__ rowptr,
                           int N) {
  __shared__ int sc[256];
  int t = threadIdx.x;
  int n = blockIdx.x * 256 + t;
  int v = (n < N) ? cursor[n] : 0;
  sc[t] = v;
  __syncthreads();
  for (int off = 1; off < 256; off <<= 1) {
    int a = (t >= off) ? sc[t - off] : 0;
    __syncthreads();
    sc[t] += a;
    __syncthreads();
  }
  int excl = partial[blockIdx.x] + sc[t] - v;
  if (n < N) {
    rowptr[n] = excl;
    cursor[n] = excl;
  }
}

// scatter src-only array (CSR order, for agg kernels)
__global__ void scatter_src(const int* __restrict__ ei,
                            int* __restrict__ cursor,
                            unsigned* __restrict__ src4, int E) {
  int e = blockIdx.x * blockDim.x + threadIdx.x;
  if (e >= E) return;
  int s = ei[e];
  int d = ei[E + e];
  int pos = atomicAdd(&cursor[d], 1);
  src4[pos] = (unsigned)s;
}

// ---- contention-free 2D bucket build: key = (dst/12500)*64 + src/1563 ----
// per-block (EPB edges) LDS histogram -> gh[blk][512]; no global atomics
__global__ __launch_bounds__(256) void bucket_hist2(const int* __restrict__ ei,
                                                    int* __restrict__ gh,
                                                    int E) {
  __shared__ int lh[512];
  int t = threadIdx.x;
  lh[t] = 0;
  lh[t + 256] = 0;
  __syncthreads();
  int base = blockIdx.x * EPB;
  for (int i = t; i < EPB; i += 256) {
    int e = base + i;
    if (e < E) {
      int s = ei[e];
      int d = ei[E + e];
      int key = (d / DDIV) * 64 + s / SDIV;
      atomicAdd(&lh[key], 1);
    }
  }
  __syncthreads();
  gh[blockIdx.x * 512 + t] = lh[t];
  gh[blockIdx.x * 512 + t + 256] = lh[t + 256];
}

// 1 block x 512 thr: thread k owns bucket k. Pass 1: per-block exclusive
// bases within bucket (reads coalesced across k). Then 512-scan -> bptr.
// Pass 2: fold bptr[k] into all per-block bases.
__global__ void bucket_scan2(int* __restrict__ gh, int* __restrict__ bptr,
                             int E, int NB) {
  __shared__ int sc[512];
  int k = threadIdx.x;
  int run = 0;
  for (int b = 0; b < NB; b++) {
    int v = gh[b * 512 + k];
    gh[b * 512 + k] = run;
    run += v;
  }
  int tot = run;
  sc[k] = tot;
  __syncthreads();
  for (int off = 1; off < 512; off <<= 1) {
    int a = (k >= off) ? sc[k - off] : 0;
    __syncthreads();
    sc[k] += a;
    __syncthreads();
  }
  int excl = sc[k] - tot;
  bptr[k] = excl;
  if (k == 0) bptr[512] = E;
  for (int b = 0; b < NB; b++) gh[b * 512 + k] += excl;
}

// scatter packed 16B record in bucket order; LDS-only rank atomics
__global__ __launch_bounds__(256) void scatter2_rec(
    const int* __restrict__ ei, const float* __restrict__ attr,
    const int* __restrict__ gh, uint4* __restrict__ rec, int E) {
  __shared__ int lcur[512];
  int t = threadIdx.x;
  lcur[t] = gh[blockIdx.x * 512 + t];
  lcur[t + 256] = gh[blockIdx.x * 512 + t + 256];
  __syncthreads();
  int base = blockIdx.x * EPB;
  for (int i = t; i < EPB; i += 256) {
    int e = base + i;
    if (e < E) {
      int s = ei[e];
      int d = ei[E + e];
      float4 a4 = *(const float4*)(attr + (size_t)e * 4);
      int key = (d / DDIV) * 64 + s / SDIV;
      int pos = atomicAdd(&lcur[key], 1);
      uint4 r;
      r.x = (unsigned)s | ((unsigned)(d & 0x7FFF) << 17);
      r.y = ((unsigned)d >> 15) | ((unsigned)e << 2);
      r.z = pack2bf(a4.x, a4.y);
      r.w = pack2bf(a4.z, a4.w);
      rec[pos] = r;
    }
  }
}

// ---- pack weights into bf16 MFMA B-fragment layouts ----
__global__ void pack_weights(const float* __restrict__ w2_root,
                             const float* __restrict__ w2_neigh,
                             const float* __restrict__ w_e1,
                             const float* __restrict__ w_e2,
                             const float* __restrict__ b_e1,
                             u16* __restrict__ B2f, u16* __restrict__ WSDf,
                             u16* __restrict__ W2f, float* __restrict__ pbias) {
  int t = blockIdx.x * 256 + threadIdx.x;
  if (t < 32768) {  // B2f: KT=8, NT=8 over [w2_root; w2_neigh] (K=256, N=128)
    int j = t & 7, lane = (t >> 3) & 63, nt = (t >> 9) & 7, kt = t >> 12;
    int k = kt * 32 + (lane >> 4) * 8 + j;
    int n = nt * 16 + (lane & 15);
    float v = (k < 128) ? w2_root[k * 128 + n] : w2_neigh[(k - 128) * 128 + n];
    B2f[t] = f2b(v);
  } else if (t < 65536) {  // WSDf: KT=4, NT=16 over [Ws | Wd] (K=128, N=256)
    int t2 = t - 32768;
    int j = t2 & 7, lane = (t2 >> 3) & 63, nt = (t2 >> 9) & 15, kt = t2 >> 13;
    int k = kt * 32 + (lane >> 4) * 8 + j;
    int n = nt * 16 + (lane & 15);
    float v = (n < 128) ? w_e1[k * 128 + n] : w_e1[(128 + k) * 128 + (n - 128)];
    WSDf[t2] = f2b(v);
  } else if (t < 73728) {  // W2f: KT=4, NT=4 over w_e2 (K=128, N=64)
    int t2 = t - 65536;
    int j = t2 & 7, lane = (t2 >> 3) & 63, nt = (t2 >> 9) & 3, kt = t2 >> 11;
    int k = kt * 32 + (lane >> 4) * 8 + j;
    int n = nt * 16 + (lane & 15);
    W2f[t2] = f2b(w_e2[k * 64 + n]);
  } else if (t < 73984) {  // pbias
    int n = t - 73728;
    pbias[n] = (n < 128) ? 0.0f : b_e1[n - 128];
  }
}

// ---- layer-1 mean aggregation: wave/node, 8 rows x 8 lanes, 4-deep ----
__global__ __launch_bounds__(256) void agg1_kernel(
    const float* __restrict__ x, const int* __restrict__ rowptr,
    const unsigned* __restrict__ src4, float* __restrict__ mean1, int N) {
  int n = blockIdx.x * 4 + (threadIdx.x >> 6);
  if (n >= N) return;
  int lane = threadIdx.x & 63;
  int g = lane >> 3;  // row group 0..7
  int c = lane & 7;   // col 0..7 (0..5 valid)
  int beg = rowptr[n], end = rowptr[n + 1];
  float a = 0.0f;
  if (c < 6) {
    int idx[4];
#pragma unroll
    for (int j = 0; j < 4; j++) {
      int ii = beg + g + j * 8;
      idx[j] = (ii < end) ? (int)src4[ii] : -1;
    }
    float v[4];
#pragma unroll
    for (int j = 0; j < 4; j++)
      v[j] = x[(size_t)(idx[j] < 0 ? 0 : idx[j]) * 6 + c];
#pragma unroll
    for (int j = 0; j < 4; j++)
      if (idx[j] >= 0) a += v[j];
    for (int ii = beg + g + 32; ii < end; ii += 8) {
      a += x[(size_t)src4[ii] * 6 + c];
    }
  }
  a += __shfl_xor(a, 8, 64);
  a += __shfl_xor(a, 16, 64);
  a += __shfl_xor(a, 32, 64);
  if (g == 0 && c < 6)
    mean1[(size_t)n * 6 + c] = a / (float)max(end - beg, 1);
}

// ---- dense layer 1 -> h1 bf16 into cat2b cols 0..127, LDS-staged ----
__global__ __launch_bounds__(256) void dense1_kernel(
    const float* __restrict__ x, const float* __restrict__ mean1,
    const float* __restrict__ w_root, const float* __restrict__ w_neigh,
    const float* __restrict__ b, u16* __restrict__ cat2b, int N) {
  __shared__ float sxm[384];  // [0:192) x for 32 nodes, [192:384) mean1
  int t = threadIdx.x;
  int col = t & 127;
  int half = t >> 7;
  float wr[6], wn[6];
#pragma unroll
  for (int j = 0; j < 6; j++) {
    wr[j] = w_root[j * 128 + col];
    wn[j] = w_neigh[j * 128 + col];
  }
  float bb = b[col];
  for (int base = blockIdx.x * 32; base < N; base += gridDim.x * 32) {
    int cnt = min(32, N - base) * 6;
    __syncthreads();
    for (int i = t; i < 384; i += 256) {
      if (i < 192)
        sxm[i] = (i < cnt) ? x[(size_t)base * 6 + i] : 0.0f;
      else
        sxm[i] = (i - 192 < cnt) ? mean1[(size_t)base * 6 + (i - 192)] : 0.0f;
    }
    __syncthreads();
#pragma unroll
    for (int sub = 0; sub < 16; sub++) {
      int nl = sub * 2 + half;
      int n = base + nl;
      if (n < N) {
        float s = bb;
#pragma unroll
        for (int j = 0; j < 6; j++)
          s += sxm[nl * 6 + j] * wr[j] + sxm[192 + nl * 6 + j] * wn[j];
        cat2b[(size_t)n * 256 + col] = f2b(fmaxf(s, 0.0f));
      }
    }
  }
}

// ---- layer-2 mean aggregation: wave/node, 4x16 lanes, 8-deep prefetch ----
__global__ __launch_bounds__(256) void agg2_kernel(
    const u16* __restrict__ cat2b, u16* __restrict__ cat2w,
    const int* __restrict__ rowptr, const unsigned* __restrict__ src4, int N) {
  int n = blockIdx.x * 4 + (threadIdx.x >> 6);
  if (n >= N) return;
  int lane = threadIdx.x & 63;
  int g = lane >> 4;  // row group 0..3
  int c = lane & 15;  // col chunk (8 bf16)
  int beg = rowptr[n], end = rowptr[n + 1];
  f32x2 acc2[4];
#pragma unroll
  for (int j = 0; j < 4; j++) acc2[j] = (f32x2){0.f, 0.f};

  const int DEPTH = 8;
  int idx[DEPTH];
#pragma unroll
  for (int j = 0; j < DEPTH; j++) {
    int ii = beg + g + j * 4;
    idx[j] = (ii < end) ? (int)src4[ii] : -1;
  }
  uint4 u[DEPTH];
#pragma unroll
  for (int j = 0; j < DEPTH; j++) {
    int s = idx[j] < 0 ? 0 : idx[j];
    u[j] = *(const uint4*)(cat2b + (size_t)s * 256 + c * 8);
  }
#pragma unroll
  for (int j = 0; j < DEPTH; j++) {
    if (idx[j] >= 0) {
      acc2[0] += unpk2(u[j].x);
      acc2[1] += unpk2(u[j].y);
      acc2[2] += unpk2(u[j].z);
      acc2[3] += unpk2(u[j].w);
    }
  }
  for (int ii = beg + g + DEPTH * 4; ii < end; ii += 4) {
    uint4 uu = *(const uint4*)(cat2b + (size_t)src4[ii] * 256 + c * 8);
    acc2[0] += unpk2(uu.x);
    acc2[1] += unpk2(uu.y);
    acc2[2] += unpk2(uu.z);
    acc2[3] += unpk2(uu.w);
  }
#pragma unroll
  for (int j = 0; j < 4; j++) {
    acc2[j].x += __shfl_xor(acc2[j].x, 16, 64);
    acc2[j].y += __shfl_xor(acc2[j].y, 16, 64);
    acc2[j].x += __shfl_xor(acc2[j].x, 32, 64);
    acc2[j].y += __shfl_xor(acc2[j].y, 32, 64);
  }
  if (g == 0) {
    float inv = 1.0f / (float)max(end - beg, 1);
    uint4 ov;
    ov.x = packrn(acc2[0] * inv);
    ov.y = packrn(acc2[1] * inv);
    ov.z = packrn(acc2[2] * inv);
    ov.w = packrn(acc2[3] * inv);
    *(uint4*)(cat2w + (size_t)n * 256 + 128 + c * 8) = ov;
  }
}

// ---- bf16 MFMA GEMM: 512 thr, 8 waves, M-tile 128 ----
template <int KT, int NT, bool RELU>
__global__ __launch_bounds__(512) void mfma_gemm(
    const u16* __restrict__ A, int lda, const u16* __restrict__ Bf,
    const float* __restrict__ bias, u16* __restrict__ C, int ldc, int M) {
  __shared__ u16 sB[KT * NT * 512];
  int tid = threadIdx.x;
  for (int i = tid; i < KT * NT * 64; i += 512)
    ((uint4*)sB)[i] = ((const uint4*)Bf)[i];
  int w = tid >> 6, l = tid & 63;
  int quad = l >> 4, col16 = l & 15;
  int rowA = blockIdx.x * 128 + w * 16 + col16;
  bool rv = rowA < M;
  const u16* ap = A + (size_t)rowA * lda + quad * 8;
  f32x4 acc[NT];
#pragma unroll
  for (int nt = 0; nt < NT; nt++) acc[nt] = (f32x4){0.f, 0.f, 0.f, 0.f};
  __syncthreads();
#pragma unroll
  for (int kt = 0; kt < KT; kt++) {
    bf16x8 av = {};
    if (rv) av = *(const bf16x8*)(ap + kt * 32);
#pragma unroll
    for (int nt = 0; nt < NT; nt++) {
      bf16x8 bv = *(const bf16x8*)(sB + ((kt * NT + nt) * 64 + l) * 8);
      acc[nt] = __builtin_amdgcn_mfma_f32_16x16x32_bf16(av, bv, acc[nt], 0, 0, 0);
    }
  }
  int rowbase = blockIdx.x * 128 + w * 16 + quad * 4;
#pragma unroll
  for (int r = 0; r < 4; r++) {
    int row = rowbase + r;
    if (row < M) {
#pragma unroll
      for (int nt = 0; nt < NT; nt++) {
        float v = acc[nt][r] + bias[nt * 16 + col16];
        if (RELU) v = fmaxf(v, 0.0f);
        C[(size_t)row * ldc + nt * 16 + col16] = f2b(v);
      }
    }
  }
}

// ---- barrier-free wave-local edge MLP over dst-stripe (XCD-pinned) ----
__global__ __launch_bounds__(256) void edge_mfma_kernel(
    const u16* __restrict__ Pcatb, const uint4* __restrict__ rec,
    const u16* __restrict__ W2f, const float* __restrict__ b_e2,
    const float* __restrict__ w_e3, const float* __restrict__ b_e3,
    const float* __restrict__ w_e1, const int* __restrict__ bptr,
    float* __restrict__ out, int E) {
  __shared__ u16 sV[64 * 136];  // 4 wave-private slices [16][136]
  __shared__ u16 sW2[8192];

  int tid = threadIdx.x;
  int w = tid >> 6, l = tid & 63, quad = l >> 4, c16 = l & 15;
  int eg = l >> 4, ac = l & 15;  // wave-local phase-A mapping
  u16* sVw = sV + w * 16 * 136;

  for (int i = tid; i < 1024; i += 256)
    ((uint4*)sW2)[i] = ((const uint4*)W2f)[i];
  __syncthreads();  // only barrier: sW2 ready; loop below is barrier-free

  // wa2[j][p2]: rows j=0..3 of Wa, column pair p2 for this thread's 8 cols
  f32x2 wa2[4][4];
#pragma unroll
  for (int j = 0; j < 4; j++) {
    float4 w0 = *(const float4*)(w_e1 + (256 + j) * 128 + ac * 8);
    float4 w1 = *(const float4*)(w_e1 + (256 + j) * 128 + ac * 8 + 4);
    wa2[j][0] = (f32x2){w0.x, w0.y};
    wa2[j][1] = (f32x2){w0.z, w0.w};
    wa2[j][2] = (f32x2){w1.x, w1.y};
    wa2[j][3] = (f32x2){w1.z, w1.w};
  }
  float w3v[4], be2[4];
#pragma unroll
  for (int nt = 0; nt < 4; nt++) {
    w3v[nt] = w_e3[nt * 16 + c16];
    be2[nt] = b_e2[nt * 16 + c16];
  }
  float b3 = b_e3[0];

  // dst-stripe = blockIdx%8 (XCD round-robin heuristic; perf-only).
  // Stripe s covers rec slots [bptr[s*64], bptr[(s+1)*64]) -> 16-edge tiles
  // [tb, te); boundary tiles double-processed (idempotent out[eid] writes).
  int s8 = blockIdx.x & 7;
  int tb = bptr[s8 * 64] >> 4;
  int te = (bptr[(s8 + 1) * 64] + 15) >> 4;
  int wi = (blockIdx.x >> 3) * 4 + w;  // wave index within stripe: 0..511
  const int NW = 512;                  // wave-stream stride within stripe
  int t = tb + wi;

  uint4 rcA[4], rcB[4];  // rec double buffer (sequential, 2 tiles deep)
  uint4 ps[4];           // rolling ps buffer: refilled for t+NW during phase A

  auto load_rec = [&](int tt, uint4* rcv) {
#pragma unroll
    for (int it = 0; it < 4; it++) {
      int e = min(tt * 16 + it * 4 + eg, E - 1);
      rcv[it] = rec[e];
    }
  };

  // process wave-tile t: cur = rec(t), nxt = rec(t+NW); on exit cur = rec(t+2NW)
  auto process = [&](int t, uint4* cur, uint4* nxt) {
    bool hasnext = (t + NW < te);
    // pd block FIRST (oldest in vmcnt FIFO): stripe rows L2-resident
    uint4 pdv[4];
#pragma unroll
    for (int it = 0; it < 4; it++) {
      int d = (int)(((cur[it].x >> 17) | (cur[it].y << 15)) & NMASK);
      pdv[it] = *(const uint4*)(Pcatb + (size_t)d * 256 + 128 + ac * 8);
    }
    // phase A: consume ps[it]/pdv[it], then refill ps[it] for tile t+NW
#pragma unroll
    for (int it = 0; it < 4; it++) {
      int e = it * 4 + eg;  // 0..15 local edge
      uint4 psu = ps[it], pdu = pdv[it];
      f32x2 a01 = unpk2(cur[it].z);
      f32x2 a23 = unpk2(cur[it].w);
      unsigned pu[4] = {psu.x, psu.y, psu.z, psu.w};
      unsigned du[4] = {pdu.x, pdu.y, pdu.z, pdu.w};
      uint4 ov;
      unsigned* op = (unsigned*)&ov;
#pragma unroll
      for (int p2 = 0; p2 < 4; p2++) {
        f32x2 f = unpk2(pu[p2]) + unpk2(du[p2]);
        f += a01.x * wa2[0][p2];
        f += a01.y * wa2[1][p2];
        f += a23.x * wa2[2][p2];
        f += a23.y * wa2[3][p2];
        f = __builtin_elementwise_max(f, (f32x2){0.f, 0.f});
        op[p2] = packrn(f);
      }
      *(uint4*)(sVw + e * 136 + ac * 8) = ov;
      if (ac == 0) *(unsigned*)(sVw + e * 136 + 128) = cur[it].y >> 2;
      if (hasnext) {
        int s = (int)(nxt[it].x & NMASK);
        ps[it] = *(const uint4*)(Pcatb + (size_t)s * 256 + ac * 8);
      }
    }
    // cur fully consumed -> reuse as rec(t+2NW) prefetch target
    if (t + 2 * NW < te) load_rec(t + 2 * NW, cur);
    // phase B: MFMA from own sV slice + relu/w3 reduce + scatter out
    f32x4 acc[4];
#pragma unroll
    for (int nt = 0; nt < 4; nt++) acc[nt] = (f32x4){0.f, 0.f, 0.f, 0.f};
    const u16* vp = sVw + c16 * 136 + quad * 8;
#pragma unroll
    for (int kt = 0; kt < 4; kt++) {
      bf16x8 av = *(const bf16x8*)(vp + kt * 32);
#pragma unroll
      for (int nt = 0; nt < 4; nt++) {
        bf16x8 bv = *(const bf16x8*)(sW2 + ((kt * 4 + nt) * 64 + l) * 8);
        acc[nt] =
            __builtin_amdgcn_mfma_f32_16x16x32_bf16(av, bv, acc[nt], 0, 0, 0);
      }
    }
#pragma unroll
    for (int r = 0; r < 4; r++) {
      float p = 0.0f;
#pragma unroll
      for (int nt = 0; nt < 4; nt++)
        p += fmaxf(acc[nt][r] + be2[nt], 0.0f) * w3v[nt];
      p += __shfl_xor(p, 1, 64);
      p += __shfl_xor(p, 2, 64);
      p += __shfl_xor(p, 4, 64);
      p += __shfl_xor(p, 8, 64);
      if (c16 == 0) {
        int eloc = quad * 4 + r;  // 0..15 local edge
        if (t * 16 + eloc < E) {
          unsigned eid = *(const unsigned*)(sVw + eloc * 136 + 128);
          out[eid] = p + b3;
        }
      }
    }
  };

  if (t >= te) return;
  // prologue: rec 2-deep, ps for first tile (full latency once)
  load_rec(t, rcA);
#pragma unroll
  for (int it = 0; it < 4; it++) {
    int s = (int)(rcA[it].x & NMASK);
    ps[it] = *(const uint4*)(Pcatb + (size_t)s * 256 + ac * 8);
  }
  if (t + NW < te) load_rec(t + NW, rcB);

  while (t < te) {
    process(t, rcA, rcB);  // consumes ps(t), refills ps from rcB, rcA<-rec(t+2NW)
    t += NW;
    if (t >= te) break;
    process(t, rcB, rcA);
    t += NW;
  }
}

extern "C" void kernel_launch(void* const* d_in, const int* in_sizes, int n_in,
                              void* d_out, int out_size, void* d_ws,
                              size_t ws_size, hipStream_t stream) {
  const float* x        = (const float*)d_in[0];
  const int*   ei       = (const int*)d_in[1];
  const float* attr     = (const float*)d_in[2];
  const float* w1_root  = (const float*)d_in[3];
  const float* w1_neigh = (const float*)d_in[4];
  const float* b1       = (const float*)d_in[5];
  const float* w2_root  = (const float*)d_in[6];
  const float* w2_neigh = (const float*)d_in[7];
  const float* b2       = (const float*)d_in[8];
  const float* w_e1     = (const float*)d_in[9];
  const float* b_e1     = (const float*)d_in[10];
  const float* w_e2     = (const float*)d_in[11];
  const float* b_e2     = (const float*)d_in[12];
  const float* w_e3     = (const float*)d_in[13];
  const float* b_e3     = (const float*)d_in[14];
  float* out = (float*)d_out;

  int N = in_sizes[0] / 6;
  int E = in_sizes[2] / 4;
  int NBLK = (N + 255) / 256;
  int NB2 = (E + EPB - 1) / EPB;  // bucket-build blocks (391 @ E=1.6M)

  int* wsi = (int*)d_ws;
  int*      rowptr  = wsi;                         // [N+1]
  int*      cursor  = wsi + 100004;                // [N]
  int*      partial = wsi + 200004;                // [512]
  unsigned* src4    = (unsigned*)(wsi + 200516);   // [E]
  uint4*    rec     = (uint4*)(wsi + 1800520);     // [E] x 16B (bucket order)
  float*    mean1   = (float*)(wsi + 8200520);     // [N,6]
  u16*      cat2b   = (u16*)(wsi + 8800520);       // [N,256] bf16
  u16*      h2b     = (u16*)(wsi + 21600520);      // [N,128] bf16
  int*      gh      = wsi + 21600520;              // [NB2*512] (h2b slot; bucket
                                                   //  build ends before gemm1)
  u16*      B2f     = (u16*)(wsi + 28000520);      // 32768 u16
  u16*      WSDf    = (u16*)(wsi + 28016904);      // 32768 u16
  u16*      W2f     = (u16*)(wsi + 28033288);      // 8192 u16
  float*    pbias   = (float*)(wsi + 28037384);    // 256 f32
  int*      bptr    = wsi + 28037640;              // [513]

  (void)hipMemsetAsync(cursor, 0, (size_t)N * sizeof(int), stream);

  pack_weights<<<289, 256, 0, stream>>>(w2_root, w2_neigh, w_e1, w_e2, b_e1,
                                        B2f, WSDf, W2f, pbias);

  // CSR build (by dst) for agg kernels
  hist_kernel<<<(E + 255) / 256, 256, 0, stream>>>(ei, cursor, E);
  scan_block_sums<<<NBLK, 256, 0, stream>>>(cursor, partial, N);
  scan_partials<<<1, 512, 0, stream>>>(partial, rowptr, NBLK, E, N);
  scan_final<<<NBLK, 256, 0, stream>>>(partial, cursor, rowptr, N);
  scatter_src<<<(E + 255) / 256, 256, 0, stream>>>(ei, cursor, src4, E);

  // contention-free 2D bucket build (8 dst-stripes x 64 src-blocks)
  bucket_hist2<<<NB2, 256, 0, stream>>>(ei, gh, E);
  bucket_scan2<<<1, 512, 0, stream>>>(gh, bptr, E, NB2);
  scatter2_rec<<<NB2, 256, 0, stream>>>(ei, attr, gh, rec, E);

  // layer 1
  agg1_kernel<<<(N + 3) / 4, 256, 0, stream>>>(x, rowptr, src4, mean1, N);
  dense1_kernel<<<1024, 256, 0, stream>>>(x, mean1, w1_root, w1_neigh, b1,
                                          cat2b, N);

  // layer 2 aggregation (8-deep pipelined bf16 gather)
  agg2_kernel<<<(N + 3) / 4, 256, 0, stream>>>(cat2b, cat2b, rowptr, src4, N);

  int gblocks = (N + 127) / 128;
  // h2 = relu([h1|mean2] @ [w2_root;w2_neigh] + b2)
  mfma_gemm<8, 8, true><<<gblocks, 512, 0, stream>>>(cat2b, 256, B2f, b2, h2b,
                                                     128, N);
  // Pcat = h2 @ [Ws|Wd] + [0|b_e1]
  mfma_gemm<4, 16, false><<<gblocks, 512, 0, stream>>>(h2b, 128, WSDf, pbias,
                                                       cat2b, 256, N);

  // stripe-local fused edge MLP (L2-resident gathers)
  edge_mfma_kernel<<<1024, 256, 0, stream>>>(cat2b, rec, W2f, b_e2, w_e3,
                                             b_e3, w_e1, bptr, out, E);
}

// Round 7
// 587.089 us; speedup vs baseline: 2.1471x; 1.3300x over previous
//
#include <hip/hip_runtime.h>
#include <hip/hip_bf16.h>
#include <stdint.h>

// ---------------------------------------------------------------------------
// UVSeamGNN R13: revert R11/R12 bucketing (verdict: edge 154 vs 149 unbucketed
// = null, build cost ~200us) back to the R10b pipeline (578.5us, edge 149.2),
// plus two safe sequential-traffic cuts:
//  1) fused_gemm: gemm1+gemm2 in one kernel via sH[128][136] bf16 LDS tile;
//     B fragments read from global (L2-broadcast; 6.5 GFLOP each, compute
//     trivial). Kills the h2b 25.6MB write + 25.6MB read. Bit-identical math
//     (same fragment order, same f2b rounding).
//  2) pack_x32: x padded 24B->32B rows so agg1's random row gathers hit
//     exactly 1 cache line each (was ~1.36). x32 lives in the freed h2b slot.
// Edge kernel = exact R10b barrier-free wave-local version (near random-gather
// ceiling: 440MB/150us = 2.9TB/s random; VALU 45% co-limiting; fp8 rejected on
// accuracy arithmetic).
// Workspace (4B words), N=100000, E=1600000:
//   rowptr @0        [N+1]
//   cursor @100004   [N]
//   partial@200004   [512]
//   src4   @200516   [E]      (src per CSR slot, for agg kernels)
//   rec    @1800520  [E*4]    (uint4: src|dstlo<<17, dsthi|eid<<2, attr01, attr23)
//   mean1  @8200520  [N*6]
//   cat2b  @8800520  [N*256]b (cols 0..127: h1/Ps; 128..255: mean2/Pd+b1)
//   x32    @21600520 [N*8]f   (freed h2b slot; 800k words)
//   B2f    @28000520 [32768]u16   WSDf @28016904 [32768]u16
//   W2f    @28033288 [8192]u16    pbias@28037384 [256]f32
// total ~112.15 MB
// ---------------------------------------------------------------------------

typedef unsigned short u16;
typedef short bf16x8 __attribute__((ext_vector_type(8)));
typedef float f32x4 __attribute__((ext_vector_type(4)));
typedef float f32x2 __attribute__((ext_vector_type(2)));

#define NMASK 0x1FFFF

__device__ __forceinline__ u16 f2b(float f) {
  unsigned u = __builtin_bit_cast(unsigned, f);
  u = u + 0x7fffu + ((u >> 16) & 1u);
  return (u16)(u >> 16);
}
__device__ __forceinline__ float bflo(unsigned u) {
  return __builtin_bit_cast(float, u << 16);
}
__device__ __forceinline__ float bfhi(unsigned u) {
  return __builtin_bit_cast(float, u & 0xffff0000u);
}
__device__ __forceinline__ f32x2 unpk2(unsigned u) {
  return (f32x2){bflo(u), bfhi(u)};
}
__device__ __forceinline__ unsigned pack2bf(float a, float b) {
  unsigned ua = __builtin_bit_cast(unsigned, a);
  unsigned ub = __builtin_bit_cast(unsigned, b);
  ua = ua + 0x7fffu + ((ua >> 16) & 1u);
  ub = ub + 0x7fffu + ((ub >> 16) & 1u);
  return (ua >> 16) | (ub & 0xffff0000u);
}
__device__ __forceinline__ unsigned packrn(f32x2 f) {
  __hip_bfloat162 h = __float22bfloat162_rn(make_float2(f.x, f.y));
  unsigned r;
  __builtin_memcpy(&r, &h, 4);
  return r;
}

// ---- CSR build ----
__global__ void hist_kernel(const int* __restrict__ ei, int* __restrict__ cnt,
                            int E) {
  int e = blockIdx.x * blockDim.x + threadIdx.x;
  if (e < E) atomicAdd(&cnt[ei[E + e]], 1);
}

__global__ void scan_block_sums(const int* __restrict__ cnt,
                                int* __restrict__ partial, int N) {
  __shared__ int red[256];
  int t = threadIdx.x;
  int n = blockIdx.x * 256 + t;
  red[t] = (n < N) ? cnt[n] : 0;
  __syncthreads();
  for (int off = 128; off; off >>= 1) {
    if (t < off) red[t] += red[t + off];
    __syncthreads();
  }
  if (t == 0) partial[blockIdx.x] = red[0];
}

__global__ void scan_partials(int* __restrict__ partial,
                              int* __restrict__ rowptr, int NBLK, int E,
                              int N) {
  __shared__ int sc[512];
  int t = threadIdx.x;
  int v = (t < NBLK) ? partial[t] : 0;
  sc[t] = v;
  __syncthreads();
  for (int off = 1; off < 512; off <<= 1) {
    int a = (t >= off) ? sc[t - off] : 0;
    __syncthreads();
    sc[t] += a;
    __syncthreads();
  }
  if (t < NBLK) partial[t] = sc[t] - v;  // exclusive
  if (t == 0) rowptr[N] = E;
}

__global__ void scan_final(const int* __restrict__ partial,
                           int* __restrict__ cursor, int* __restrict__ rowptr,
                           int N) {
  __shared__ int sc[256];
  int t = threadIdx.x;
  int n = blockIdx.x * 256 + t;
  int v = (n < N) ? cursor[n] : 0;
  sc[t] = v;
  __syncthreads();
  for (int off = 1; off < 256; off <<= 1) {
    int a = (t >= off) ? sc[t - off] : 0;
    __syncthreads();
    sc[t] += a;
    __syncthreads();
  }
  int excl = partial[blockIdx.x] + sc[t] - v;
  if (n < N) {
    rowptr[n] = excl;
    cursor[n] = excl;
  }
}

// scatter packed 16B record + src-only array in one pass
__global__ void scatter_rec(const int* __restrict__ ei,
                            const float* __restrict__ attr,
                            int* __restrict__ cursor, uint4* __restrict__ rec,
                            unsigned* __restrict__ src4, int E) {
  int e = blockIdx.x * blockDim.x + threadIdx.x;
  if (e >= E) return;
  int s = ei[e];
  int d = ei[E + e];
  float4 a4 = *(const float4*)(attr + (size_t)e * 4);
  int pos = atomicAdd(&cursor[d], 1);
  uint4 r;
  r.x = (unsigned)s | ((unsigned)(d & 0x7FFF) << 17);
  r.y = ((unsigned)d >> 15) | ((unsigned)e << 2);
  r.z = pack2bf(a4.x, a4.y);
  r.w = pack2bf(a4.z, a4.w);
  rec[pos] = r;
  src4[pos] = (unsigned)s;
}

// ---- pad x [N,6] f32 -> x32 [N,8] f32 (1-line rows for agg1 gathers) ----
__global__ void pack_x32(const float* __restrict__ x, float* __restrict__ x32,
                         int N) {
  int i = blockIdx.x * blockDim.x + threadIdx.x;
  if (i >= N * 8) return;
  int c = i & 7;
  x32[i] = (c < 6) ? x[(size_t)(i >> 3) * 6 + c] : 0.0f;
}

// ---- pack weights into bf16 MFMA B-fragment layouts ----
__global__ void pack_weights(const float* __restrict__ w2_root,
                             const float* __restrict__ w2_neigh,
                             const float* __restrict__ w_e1,
                             const float* __restrict__ w_e2,
                             const float* __restrict__ b_e1,
                             u16* __restrict__ B2f, u16* __restrict__ WSDf,
                             u16* __restrict__ W2f, float* __restrict__ pbias) {
  int t = blockIdx.x * 256 + threadIdx.x;
  if (t < 32768) {  // B2f: KT=8, NT=8 over [w2_root; w2_neigh] (K=256, N=128)
    int j = t & 7, lane = (t >> 3) & 63, nt = (t >> 9) & 7, kt = t >> 12;
    int k = kt * 32 + (lane >> 4) * 8 + j;
    int n = nt * 16 + (lane & 15);
    float v = (k < 128) ? w2_root[k * 128 + n] : w2_neigh[(k - 128) * 128 + n];
    B2f[t] = f2b(v);
  } else if (t < 65536) {  // WSDf: KT=4, NT=16 over [Ws | Wd] (K=128, N=256)
    int t2 = t - 32768;
    int j = t2 & 7, lane = (t2 >> 3) & 63, nt = (t2 >> 9) & 15, kt = t2 >> 13;
    int k = kt * 32 + (lane >> 4) * 8 + j;
    int n = nt * 16 + (lane & 15);
    float v = (n < 128) ? w_e1[k * 128 + n] : w_e1[(128 + k) * 128 + (n - 128)];
    WSDf[t2] = f2b(v);
  } else if (t < 73728) {  // W2f: KT=4, NT=4 over w_e2 (K=128, N=64)
    int t2 = t - 65536;
    int j = t2 & 7, lane = (t2 >> 3) & 63, nt = (t2 >> 9) & 3, kt = t2 >> 11;
    int k = kt * 32 + (lane >> 4) * 8 + j;
    int n = nt * 16 + (lane & 15);
    W2f[t2] = f2b(w_e2[k * 64 + n]);
  } else if (t < 73984) {  // pbias
    int n = t - 73728;
    pbias[n] = (n < 128) ? 0.0f : b_e1[n - 128];
  }
}

// ---- layer-1 mean aggregation: wave/node, 8 rows x 8 lanes, 4-deep ----
__global__ __launch_bounds__(256) void agg1_kernel(
    const float* __restrict__ x32, const int* __restrict__ rowptr,
    const unsigned* __restrict__ src4, float* __restrict__ mean1, int N) {
  int n = blockIdx.x * 4 + (threadIdx.x >> 6);
  if (n >= N) return;
  int lane = threadIdx.x & 63;
  int g = lane >> 3;  // row group 0..7
  int c = lane & 7;   // col 0..7 (0..5 valid)
  int beg = rowptr[n], end = rowptr[n + 1];
  float a = 0.0f;
  if (c < 6) {
    int idx[4];
#pragma unroll
    for (int j = 0; j < 4; j++) {
      int ii = beg + g + j * 8;
      idx[j] = (ii < end) ? (int)src4[ii] : -1;
    }
    float v[4];
#pragma unroll
    for (int j = 0; j < 4; j++)
      v[j] = x32[(size_t)(idx[j] < 0 ? 0 : idx[j]) * 8 + c];
#pragma unroll
    for (int j = 0; j < 4; j++)
      if (idx[j] >= 0) a += v[j];
    for (int ii = beg + g + 32; ii < end; ii += 8) {
      a += x32[(size_t)src4[ii] * 8 + c];
    }
  }
  a += __shfl_xor(a, 8, 64);
  a += __shfl_xor(a, 16, 64);
  a += __shfl_xor(a, 32, 64);
  if (g == 0 && c < 6)
    mean1[(size_t)n * 6 + c] = a / (float)max(end - beg, 1);
}

// ---- dense layer 1 -> h1 bf16 into cat2b cols 0..127, LDS-staged ----
__global__ __launch_bounds__(256) void dense1_kernel(
    const float* __restrict__ x, const float* __restrict__ mean1,
    const float* __restrict__ w_root, const float* __restrict__ w_neigh,
    const float* __restrict__ b, u16* __restrict__ cat2b, int N) {
  __shared__ float sxm[384];  // [0:192) x for 32 nodes, [192:384) mean1
  int t = threadIdx.x;
  int col = t & 127;
  int half = t >> 7;
  float wr[6], wn[6];
#pragma unroll
  for (int j = 0; j < 6; j++) {
    wr[j] = w_root[j * 128 + col];
    wn[j] = w_neigh[j * 128 + col];
  }
  float bb = b[col];
  for (int base = blockIdx.x * 32; base < N; base += gridDim.x * 32) {
    int cnt = min(32, N - base) * 6;
    __syncthreads();
    for (int i = t; i < 384; i += 256) {
      if (i < 192)
        sxm[i] = (i < cnt) ? x[(size_t)base * 6 + i] : 0.0f;
      else
        sxm[i] = (i - 192 < cnt) ? mean1[(size_t)base * 6 + (i - 192)] : 0.0f;
    }
    __syncthreads();
#pragma unroll
    for (int sub = 0; sub < 16; sub++) {
      int nl = sub * 2 + half;
      int n = base + nl;
      if (n < N) {
        float s = bb;
#pragma unroll
        for (int j = 0; j < 6; j++)
          s += sxm[nl * 6 + j] * wr[j] + sxm[192 + nl * 6 + j] * wn[j];
        cat2b[(size_t)n * 256 + col] = f2b(fmaxf(s, 0.0f));
      }
    }
  }
}

// ---- layer-2 mean aggregation: wave/node, 4x16 lanes, 8-deep prefetch ----
__global__ __launch_bounds__(256) void agg2_kernel(
    const u16* __restrict__ cat2b, u16* __restrict__ cat2w,
    const int* __restrict__ rowptr, const unsigned* __restrict__ src4, int N) {
  int n = blockIdx.x * 4 + (threadIdx.x >> 6);
  if (n >= N) return;
  int lane = threadIdx.x & 63;
  int g = lane >> 4;  // row group 0..3
  int c = lane & 15;  // col chunk (8 bf16)
  int beg = rowptr[n], end = rowptr[n + 1];
  f32x2 acc2[4];
#pragma unroll
  for (int j = 0; j < 4; j++) acc2[j] = (f32x2){0.f, 0.f};

  const int DEPTH = 8;
  int idx[DEPTH];
#pragma unroll
  for (int j = 0; j < DEPTH; j++) {
    int ii = beg + g + j * 4;
    idx[j] = (ii < end) ? (int)src4[ii] : -1;
  }
  uint4 u[DEPTH];
#pragma unroll
  for (int j = 0; j < DEPTH; j++) {
    int s = idx[j] < 0 ? 0 : idx[j];
    u[j] = *(const uint4*)(cat2b + (size_t)s * 256 + c * 8);
  }
#pragma unroll
  for (int j = 0; j < DEPTH; j++) {
    if (idx[j] >= 0) {
      acc2[0] += unpk2(u[j].x);
      acc2[1] += unpk2(u[j].y);
      acc2[2] += unpk2(u[j].z);
      acc2[3] += unpk2(u[j].w);
    }
  }
  for (int ii = beg + g + DEPTH * 4; ii < end; ii += 4) {
    uint4 uu = *(const uint4*)(cat2b + (size_t)src4[ii] * 256 + c * 8);
    acc2[0] += unpk2(uu.x);
    acc2[1] += unpk2(uu.y);
    acc2[2] += unpk2(uu.z);
    acc2[3] += unpk2(uu.w);
  }
#pragma unroll
  for (int j = 0; j < 4; j++) {
    acc2[j].x += __shfl_xor(acc2[j].x, 16, 64);
    acc2[j].y += __shfl_xor(acc2[j].y, 16, 64);
    acc2[j].x += __shfl_xor(acc2[j].x, 32, 64);
    acc2[j].y += __shfl_xor(acc2[j].y, 32, 64);
  }
  if (g == 0) {
    float inv = 1.0f / (float)max(end - beg, 1);
    uint4 ov;
    ov.x = packrn(acc2[0] * inv);
    ov.y = packrn(acc2[1] * inv);
    ov.z = packrn(acc2[2] * inv);
    ov.w = packrn(acc2[3] * inv);
    *(uint4*)(cat2w + (size_t)n * 256 + 128 + c * 8) = ov;
  }
}

// ---- fused node GEMMs: h2 = relu(cat2b@[B2f]+b2) (LDS), Pcat = h2@WSD+pbias
// B fragments read from global (L2-broadcast). sH stride 136 u16 keeps b128
// reads 16B-aligned and ~2-way banked. Bit-identical to the split kernels.
__global__ __launch_bounds__(512) void fused_gemm(
    const u16* __restrict__ A, const u16* __restrict__ B1f,
    const float* __restrict__ b2, const u16* __restrict__ BSDf,
    const float* __restrict__ pbias, u16* __restrict__ C, int M) {
  __shared__ u16 sH[128 * 136];
  int tid = threadIdx.x;
  int w = tid >> 6, l = tid & 63;
  int quad = l >> 4, col16 = l & 15;
  int rowA = blockIdx.x * 128 + w * 16 + col16;
  bool rv = rowA < M;
  const u16* ap = A + (size_t)rowA * 256 + quad * 8;
  // GEMM1: 128 rows x 128 cols, K=256
  f32x4 acc1[8];
#pragma unroll
  for (int nt = 0; nt < 8; nt++) acc1[nt] = (f32x4){0.f, 0.f, 0.f, 0.f};
#pragma unroll
  for (int kt = 0; kt < 8; kt++) {
    bf16x8 av = {};
    if (rv) av = *(const bf16x8*)(ap + kt * 32);
#pragma unroll
    for (int nt = 0; nt < 8; nt++) {
      bf16x8 bv = *(const bf16x8*)(B1f + ((kt * 8 + nt) * 64 + l) * 8);
      acc1[nt] = __builtin_amdgcn_mfma_f32_16x16x32_bf16(av, bv, acc1[nt], 0, 0, 0);
    }
  }
  int rowb = w * 16 + quad * 4;  // local row base
#pragma unroll
  for (int r = 0; r < 4; r++) {
#pragma unroll
    for (int nt = 0; nt < 8; nt++) {
      float v = acc1[nt][r] + b2[nt * 16 + col16];
      sH[(rowb + r) * 136 + nt * 16 + col16] = f2b(fmaxf(v, 0.0f));
    }
  }
  __syncthreads();
  // GEMM2: 128 rows x 256 cols, K=128 from sH
  const u16* hp = sH + (w * 16 + col16) * 136 + quad * 8;
  f32x4 acc2[16];
#pragma unroll
  for (int nt = 0; nt < 16; nt++) acc2[nt] = (f32x4){0.f, 0.f, 0.f, 0.f};
#pragma unroll
  for (int kt = 0; kt < 4; kt++) {
    bf16x8 av = *(const bf16x8*)(hp + kt * 32);
#pragma unroll
    for (int nt = 0; nt < 16; nt++) {
      bf16x8 bv = *(const bf16x8*)(BSDf + ((kt * 16 + nt) * 64 + l) * 8);
      acc2[nt] = __builtin_amdgcn_mfma_f32_16x16x32_bf16(av, bv, acc2[nt], 0, 0, 0);
    }
  }
#pragma unroll
  for (int r = 0; r < 4; r++) {
    int row = blockIdx.x * 128 + rowb + r;
    if (row < M) {
#pragma unroll
      for (int nt = 0; nt < 16; nt++)
        C[(size_t)row * 256 + nt * 16 + col16] =
            f2b(acc2[nt][r] + pbias[nt * 16 + col16]);
    }
  }
}

// ---- barrier-free wave-local edge MLP: 16 edges/wave-tile, private sV ----
__global__ __launch_bounds__(256) void edge_mfma_kernel(
    const u16* __restrict__ Pcatb, const uint4* __restrict__ rec,
    const u16* __restrict__ W2f, const float* __restrict__ b_e2,
    const float* __restrict__ w_e3, const float* __restrict__ b_e3,
    const float* __restrict__ w_e1, float* __restrict__ out, int E) {
  __shared__ u16 sV[64 * 136];  // 4 wave-private slices [16][136]
  __shared__ u16 sW2[8192];

  int tid = threadIdx.x;
  int w = tid >> 6, l = tid & 63, quad = l >> 4, c16 = l & 15;
  int eg = l >> 4, ac = l & 15;  // wave-local phase-A mapping
  u16* sVw = sV + w * 16 * 136;

  for (int i = tid; i < 1024; i += 256)
    ((uint4*)sW2)[i] = ((const uint4*)W2f)[i];
  __syncthreads();  // only barrier: sW2 ready; loop below is barrier-free

  // wa2[j][p2]: rows j=0..3 of Wa, column pair p2 for this thread's 8 cols
  f32x2 wa2[4][4];
#pragma unroll
  for (int j = 0; j < 4; j++) {
    float4 w0 = *(const float4*)(w_e1 + (256 + j) * 128 + ac * 8);
    float4 w1 = *(const float4*)(w_e1 + (256 + j) * 128 + ac * 8 + 4);
    wa2[j][0] = (f32x2){w0.x, w0.y};
    wa2[j][1] = (f32x2){w0.z, w0.w};
    wa2[j][2] = (f32x2){w1.x, w1.y};
    wa2[j][3] = (f32x2){w1.z, w1.w};
  }
  float w3v[4], be2[4];
#pragma unroll
  for (int nt = 0; nt < 4; nt++) {
    w3v[nt] = w_e3[nt * 16 + c16];
    be2[nt] = b_e2[nt * 16 + c16];
  }
  float b3 = b_e3[0];

  int tiles = (E + 15) >> 4;      // 16-edge wave tiles
  int NW = gridDim.x * 4;         // wave-stream stride
  int t = blockIdx.x * 4 + w;

  uint4 rcA[4], rcB[4];  // rec double buffer (sequential, 2 tiles deep)
  uint4 ps[4];           // rolling ps buffer: refilled for t+NW during phase A

  auto load_rec = [&](int tt, uint4* rcv) {
#pragma unroll
    for (int it = 0; it < 4; it++) {
      int e = min(tt * 16 + it * 4 + eg, E - 1);
      rcv[it] = rec[e];
    }
  };

  // process wave-tile t: cur = rec(t), nxt = rec(t+NW); on exit cur = rec(t+2NW)
  auto process = [&](int t, uint4* cur, uint4* nxt) {
    bool hasnext = (t + NW < tiles);
    // pd block FIRST (oldest in vmcnt FIFO): dst-sorted -> cache-hot
    uint4 pdv[4];
#pragma unroll
    for (int it = 0; it < 4; it++) {
      int d = (int)(((cur[it].x >> 17) | (cur[it].y << 15)) & NMASK);
      pdv[it] = *(const uint4*)(Pcatb + (size_t)d * 256 + 128 + ac * 8);
    }
    // phase A: consume ps[it]/pdv[it], then refill ps[it] for tile t+NW
#pragma unroll
    for (int it = 0; it < 4; it++) {
      int e = it * 4 + eg;  // 0..15 local edge
      uint4 psu = ps[it], pdu = pdv[it];
      f32x2 a01 = unpk2(cur[it].z);
      f32x2 a23 = unpk2(cur[it].w);
      unsigned pu[4] = {psu.x, psu.y, psu.z, psu.w};
      unsigned du[4] = {pdu.x, pdu.y, pdu.z, pdu.w};
      uint4 ov;
      unsigned* op = (unsigned*)&ov;
#pragma unroll
      for (int p2 = 0; p2 < 4; p2++) {
        f32x2 f = unpk2(pu[p2]) + unpk2(du[p2]);
        f += a01.x * wa2[0][p2];
        f += a01.y * wa2[1][p2];
        f += a23.x * wa2[2][p2];
        f += a23.y * wa2[3][p2];
        f = __builtin_elementwise_max(f, (f32x2){0.f, 0.f});
        op[p2] = packrn(f);
      }
      *(uint4*)(sVw + e * 136 + ac * 8) = ov;
      if (ac == 0) *(unsigned*)(sVw + e * 136 + 128) = cur[it].y >> 2;
      if (hasnext) {
        int s = (int)(nxt[it].x & NMASK);
        ps[it] = *(const uint4*)(Pcatb + (size_t)s * 256 + ac * 8);
      }
    }
    // cur fully consumed -> reuse as rec(t+2NW) prefetch target
    if (t + 2 * NW < tiles) load_rec(t + 2 * NW, cur);
    // phase B: MFMA from own sV slice (same-wave write->read; compiler
    // inserts the lgkmcnt wait) + relu/w3 reduce + scatter out
    f32x4 acc[4];
#pragma unroll
    for (int nt = 0; nt < 4; nt++) acc[nt] = (f32x4){0.f, 0.f, 0.f, 0.f};
    const u16* vp = sVw + c16 * 136 + quad * 8;
#pragma unroll
    for (int kt = 0; kt < 4; kt++) {
      bf16x8 av = *(const bf16x8*)(vp + kt * 32);
#pragma unroll
      for (int nt = 0; nt < 4; nt++) {
        bf16x8 bv = *(const bf16x8*)(sW2 + ((kt * 4 + nt) * 64 + l) * 8);
        acc[nt] =
            __builtin_amdgcn_mfma_f32_16x16x32_bf16(av, bv, acc[nt], 0, 0, 0);
      }
    }
#pragma unroll
    for (int r = 0; r < 4; r++) {
      float p = 0.0f;
#pragma unroll
      for (int nt = 0; nt < 4; nt++)
        p += fmaxf(acc[nt][r] + be2[nt], 0.0f) * w3v[nt];
      p += __shfl_xor(p, 1, 64);
      p += __shfl_xor(p, 2, 64);
      p += __shfl_xor(p, 4, 64);
      p += __shfl_xor(p, 8, 64);
      if (c16 == 0) {
        int eloc = quad * 4 + r;  // 0..15 local edge
        if (t * 16 + eloc < E) {
          unsigned eid = *(const unsigned*)(sVw + eloc * 136 + 128);
          out[eid] = p + b3;
        }
      }
    }
  };

  if (t >= tiles) return;
  // prologue: rec 2-deep, ps for first tile (full latency once)
  load_rec(t, rcA);
#pragma unroll
  for (int it = 0; it < 4; it++) {
    int s = (int)(rcA[it].x & NMASK);
    ps[it] = *(const uint4*)(Pcatb + (size_t)s * 256 + ac * 8);
  }
  if (t + NW < tiles) load_rec(t + NW, rcB);

  while (t < tiles) {
    process(t, rcA, rcB);  // consumes ps(t), refills ps from rcB, rcA<-rec(t+2NW)
    t += NW;
    if (t >= tiles) break;
    process(t, rcB, rcA);
    t += NW;
  }
}

extern "C" void kernel_launch(void* const* d_in, const int* in_sizes, int n_in,
                              void* d_out, int out_size, void* d_ws,
                              size_t ws_size, hipStream_t stream) {
  const float* x        = (const float*)d_in[0];
  const int*   ei       = (const int*)d_in[1];
  const float* attr     = (const float*)d_in[2];
  const float* w1_root  = (const float*)d_in[3];
  const float* w1_neigh = (const float*)d_in[4];
  const float* b1       = (const float*)d_in[5];
  const float* w2_root  = (const float*)d_in[6];
  const float* w2_neigh = (const float*)d_in[7];
  const float* b2       = (const float*)d_in[8];
  const float* w_e1     = (const float*)d_in[9];
  const float* b_e1     = (const float*)d_in[10];
  const float* w_e2     = (const float*)d_in[11];
  const float* b_e2     = (const float*)d_in[12];
  const float* w_e3     = (const float*)d_in[13];
  const float* b_e3     = (const float*)d_in[14];
  float* out = (float*)d_out;

  int N = in_sizes[0] / 6;
  int E = in_sizes[2] / 4;
  int NBLK = (N + 255) / 256;

  int* wsi = (int*)d_ws;
  int*      rowptr  = wsi;                         // [N+1]
  int*      cursor  = wsi + 100004;                // [N]
  int*      partial = wsi + 200004;                // [512]
  unsigned* src4    = (unsigned*)(wsi + 200516);   // [E]
  uint4*    rec     = (uint4*)(wsi + 1800520);     // [E] x 16B
  float*    mean1   = (float*)(wsi + 8200520);     // [N,6]
  u16*      cat2b   = (u16*)(wsi + 8800520);       // [N,256] bf16
  float*    x32     = (float*)(wsi + 21600520);    // [N,8] f32 (freed h2b slot)
  u16*      B2f     = (u16*)(wsi + 28000520);      // 32768 u16
  u16*      WSDf    = (u16*)(wsi + 28016904);      // 32768 u16
  u16*      W2f     = (u16*)(wsi + 28033288);      // 8192 u16
  float*    pbias   = (float*)(wsi + 28037384);    // 256 f32

  (void)hipMemsetAsync(cursor, 0, (size_t)N * sizeof(int), stream);

  pack_weights<<<289, 256, 0, stream>>>(w2_root, w2_neigh, w_e1, w_e2, b_e1,
                                        B2f, WSDf, W2f, pbias);
  pack_x32<<<(N * 8 + 255) / 256, 256, 0, stream>>>(x, x32, N);

  // CSR build (by dst), attr packed into 16B records
  hist_kernel<<<(E + 255) / 256, 256, 0, stream>>>(ei, cursor, E);
  scan_block_sums<<<NBLK, 256, 0, stream>>>(cursor, partial, N);
  scan_partials<<<1, 512, 0, stream>>>(partial, rowptr, NBLK, E, N);
  scan_final<<<NBLK, 256, 0, stream>>>(partial, cursor, rowptr, N);
  scatter_rec<<<(E + 255) / 256, 256, 0, stream>>>(ei, attr, cursor, rec,
                                                   src4, E);

  // layer 1
  agg1_kernel<<<(N + 3) / 4, 256, 0, stream>>>(x32, rowptr, src4, mean1, N);
  dense1_kernel<<<1024, 256, 0, stream>>>(x, mean1, w1_root, w1_neigh, b1,
                                          cat2b, N);

  // layer 2 aggregation (8-deep pipelined bf16 gather)
  agg2_kernel<<<(N + 3) / 4, 256, 0, stream>>>(cat2b, cat2b, rowptr, src4, N);

  // fused: h2 = relu([h1|mean2]@[w2_root;w2_neigh]+b2); Pcat = h2@[Ws|Wd]+[0|b_e1]
  fused_gemm<<<(N + 127) / 128, 512, 0, stream>>>(cat2b, B2f, b2, WSDf, pbias,
                                                  cat2b, N);

  // barrier-free wave-local fused edge MLP
  edge_mfma_kernel<<<1024, 256, 0, stream>>>(cat2b, rec, W2f, b_e2, w_e3,
                                             b_e3, w_e1, out, E);
}

// Round 8
// 580.565 us; speedup vs baseline: 2.1713x; 1.0112x over previous
//
#include <hip/hip_runtime.h>
#include <hip/hip_bf16.h>
#include <stdint.h>

// ---------------------------------------------------------------------------
// UVSeamGNN R14: revert R13's fused_gemm (regression: +15us vs split -- B
// fragments streamed from global inside the MFMA loop with 96 acc VGPRs,
// no LDS staging), restoring R10b's split mfma_gemm pair (LDS-staged B).
// KEEP pack_x32 + agg1-on-x32 (R13's likely-positive delta: 1 line per
// random x-row gather instead of ~1.36).
// x32 ALIASES the h2b region: lifetimes disjoint (x32 written by pack_x32,
// consumed by agg1; h2b first written by gemm1 which runs strictly after
// agg1; stream-serialized within and across graph iterations).
// Edge kernel = R10b barrier-free wave-local version, pinned at 149-150us
// across 4 orthogonal attacks -> random-line request-throughput ceiling
// (~43G lines/s), insensitive to cache level; fp8 parked on accuracy.
// Workspace (4B words), N=100000, E=1600000:
//   rowptr @0        [N+1]
//   cursor @100004   [N]
//   partial@200004   [512]
//   src4   @200516   [E]      (src per CSR slot, for agg kernels)
//   rec    @1800520  [E*4]    (uint4: src|dstlo<<17, dsthi|eid<<2, attr01, attr23)
//   mean1  @8200520  [N*6]
//   cat2b  @8800520  [N*256]b (cols 0..127: h1/Ps; 128..255: mean2/Pd+b1)
//   x32    @21600520 [N*8]f   (aliases h2b; dead before gemm1 writes h2b)
//   h2b    @21600520 [N*128]b (6.4M words -> ends 28000520)
//   B2f    @28000520 [32768]u16   WSDf @28016904 [32768]u16
//   W2f    @28033288 [8192]u16    pbias@28037384 [256]f32
// total ~112.15 MB
// ---------------------------------------------------------------------------

typedef unsigned short u16;
typedef short bf16x8 __attribute__((ext_vector_type(8)));
typedef float f32x4 __attribute__((ext_vector_type(4)));
typedef float f32x2 __attribute__((ext_vector_type(2)));

#define NMASK 0x1FFFF

__device__ __forceinline__ u16 f2b(float f) {
  unsigned u = __builtin_bit_cast(unsigned, f);
  u = u + 0x7fffu + ((u >> 16) & 1u);
  return (u16)(u >> 16);
}
__device__ __forceinline__ float bflo(unsigned u) {
  return __builtin_bit_cast(float, u << 16);
}
__device__ __forceinline__ float bfhi(unsigned u) {
  return __builtin_bit_cast(float, u & 0xffff0000u);
}
__device__ __forceinline__ f32x2 unpk2(unsigned u) {
  return (f32x2){bflo(u), bfhi(u)};
}
__device__ __forceinline__ unsigned pack2bf(float a, float b) {
  unsigned ua = __builtin_bit_cast(unsigned, a);
  unsigned ub = __builtin_bit_cast(unsigned, b);
  ua = ua + 0x7fffu + ((ua >> 16) & 1u);
  ub = ub + 0x7fffu + ((ub >> 16) & 1u);
  return (ua >> 16) | (ub & 0xffff0000u);
}
__device__ __forceinline__ unsigned packrn(f32x2 f) {
  __hip_bfloat162 h = __float22bfloat162_rn(make_float2(f.x, f.y));
  unsigned r;
  __builtin_memcpy(&r, &h, 4);
  return r;
}

// ---- CSR build ----
__global__ void hist_kernel(const int* __restrict__ ei, int* __restrict__ cnt,
                            int E) {
  int e = blockIdx.x * blockDim.x + threadIdx.x;
  if (e < E) atomicAdd(&cnt[ei[E + e]], 1);
}

__global__ void scan_block_sums(const int* __restrict__ cnt,
                                int* __restrict__ partial, int N) {
  __shared__ int red[256];
  int t = threadIdx.x;
  int n = blockIdx.x * 256 + t;
  red[t] = (n < N) ? cnt[n] : 0;
  __syncthreads();
  for (int off = 128; off; off >>= 1) {
    if (t < off) red[t] += red[t + off];
    __syncthreads();
  }
  if (t == 0) partial[blockIdx.x] = red[0];
}

__global__ void scan_partials(int* __restrict__ partial,
                              int* __restrict__ rowptr, int NBLK, int E,
                              int N) {
  __shared__ int sc[512];
  int t = threadIdx.x;
  int v = (t < NBLK) ? partial[t] : 0;
  sc[t] = v;
  __syncthreads();
  for (int off = 1; off < 512; off <<= 1) {
    int a = (t >= off) ? sc[t - off] : 0;
    __syncthreads();
    sc[t] += a;
    __syncthreads();
  }
  if (t < NBLK) partial[t] = sc[t] - v;  // exclusive
  if (t == 0) rowptr[N] = E;
}

__global__ void scan_final(const int* __restrict__ partial,
                           int* __restrict__ cursor, int* __restrict__ rowptr,
                           int N) {
  __shared__ int sc[256];
  int t = threadIdx.x;
  int n = blockIdx.x * 256 + t;
  int v = (n < N) ? cursor[n] : 0;
  sc[t] = v;
  __syncthreads();
  for (int off = 1; off < 256; off <<= 1) {
    int a = (t >= off) ? sc[t - off] : 0;
    __syncthreads();
    sc[t] += a;
    __syncthreads();
  }
  int excl = partial[blockIdx.x] + sc[t] - v;
  if (n < N) {
    rowptr[n] = excl;
    cursor[n] = excl;
  }
}

// scatter packed 16B record + src-only array in one pass
__global__ void scatter_rec(const int* __restrict__ ei,
                            const float* __restrict__ attr,
                            int* __restrict__ cursor, uint4* __restrict__ rec,
                            unsigned* __restrict__ src4, int E) {
  int e = blockIdx.x * blockDim.x + threadIdx.x;
  if (e >= E) return;
  int s = ei[e];
  int d = ei[E + e];
  float4 a4 = *(const float4*)(attr + (size_t)e * 4);
  int pos = atomicAdd(&cursor[d], 1);
  uint4 r;
  r.x = (unsigned)s | ((unsigned)(d & 0x7FFF) << 17);
  r.y = ((unsigned)d >> 15) | ((unsigned)e << 2);
  r.z = pack2bf(a4.x, a4.y);
  r.w = pack2bf(a4.z, a4.w);
  rec[pos] = r;
  src4[pos] = (unsigned)s;
}

// ---- pad x [N,6] f32 -> x32 [N,8] f32 (1-line rows for agg1 gathers) ----
__global__ void pack_x32(const float* __restrict__ x, float* __restrict__ x32,
                         int N) {
  int i = blockIdx.x * blockDim.x + threadIdx.x;
  if (i >= N * 8) return;
  int c = i & 7;
  x32[i] = (c < 6) ? x[(size_t)(i >> 3) * 6 + c] : 0.0f;
}

// ---- pack weights into bf16 MFMA B-fragment layouts ----
__global__ void pack_weights(const float* __restrict__ w2_root,
                             const float* __restrict__ w2_neigh,
                             const float* __restrict__ w_e1,
                             const float* __restrict__ w_e2,
                             const float* __restrict__ b_e1,
                             u16* __restrict__ B2f, u16* __restrict__ WSDf,
                             u16* __restrict__ W2f, float* __restrict__ pbias) {
  int t = blockIdx.x * 256 + threadIdx.x;
  if (t < 32768) {  // B2f: KT=8, NT=8 over [w2_root; w2_neigh] (K=256, N=128)
    int j = t & 7, lane = (t >> 3) & 63, nt = (t >> 9) & 7, kt = t >> 12;
    int k = kt * 32 + (lane >> 4) * 8 + j;
    int n = nt * 16 + (lane & 15);
    float v = (k < 128) ? w2_root[k * 128 + n] : w2_neigh[(k - 128) * 128 + n];
    B2f[t] = f2b(v);
  } else if (t < 65536) {  // WSDf: KT=4, NT=16 over [Ws | Wd] (K=128, N=256)
    int t2 = t - 32768;
    int j = t2 & 7, lane = (t2 >> 3) & 63, nt = (t2 >> 9) & 15, kt = t2 >> 13;
    int k = kt * 32 + (lane >> 4) * 8 + j;
    int n = nt * 16 + (lane & 15);
    float v = (n < 128) ? w_e1[k * 128 + n] : w_e1[(128 + k) * 128 + (n - 128)];
    WSDf[t2] = f2b(v);
  } else if (t < 73728) {  // W2f: KT=4, NT=4 over w_e2 (K=128, N=64)
    int t2 = t - 65536;
    int j = t2 & 7, lane = (t2 >> 3) & 63, nt = (t2 >> 9) & 3, kt = t2 >> 11;
    int k = kt * 32 + (lane >> 4) * 8 + j;
    int n = nt * 16 + (lane & 15);
    W2f[t2] = f2b(w_e2[k * 64 + n]);
  } else if (t < 73984) {  // pbias
    int n = t - 73728;
    pbias[n] = (n < 128) ? 0.0f : b_e1[n - 128];
  }
}

// ---- layer-1 mean aggregation: wave/node, 8 rows x 8 lanes, 4-deep ----
__global__ __launch_bounds__(256) void agg1_kernel(
    const float* __restrict__ x32, const int* __restrict__ rowptr,
    const unsigned* __restrict__ src4, float* __restrict__ mean1, int N) {
  int n = blockIdx.x * 4 + (threadIdx.x >> 6);
  if (n >= N) return;
  int lane = threadIdx.x & 63;
  int g = lane >> 3;  // row group 0..7
  int c = lane & 7;   // col 0..7 (0..5 valid)
  int beg = rowptr[n], end = rowptr[n + 1];
  float a = 0.0f;
  if (c < 6) {
    int idx[4];
#pragma unroll
    for (int j = 0; j < 4; j++) {
      int ii = beg + g + j * 8;
      idx[j] = (ii < end) ? (int)src4[ii] : -1;
    }
    float v[4];
#pragma unroll
    for (int j = 0; j < 4; j++)
      v[j] = x32[(size_t)(idx[j] < 0 ? 0 : idx[j]) * 8 + c];
#pragma unroll
    for (int j = 0; j < 4; j++)
      if (idx[j] >= 0) a += v[j];
    for (int ii = beg + g + 32; ii < end; ii += 8) {
      a += x32[(size_t)src4[ii] * 8 + c];
    }
  }
  a += __shfl_xor(a, 8, 64);
  a += __shfl_xor(a, 16, 64);
  a += __shfl_xor(a, 32, 64);
  if (g == 0 && c < 6)
    mean1[(size_t)n * 6 + c] = a / (float)max(end - beg, 1);
}

// ---- dense layer 1 -> h1 bf16 into cat2b cols 0..127, LDS-staged ----
__global__ __launch_bounds__(256) void dense1_kernel(
    const float* __restrict__ x, const float* __restrict__ mean1,
    const float* __restrict__ w_root, const float* __restrict__ w_neigh,
    const float* __restrict__ b, u16* __restrict__ cat2b, int N) {
  __shared__ float sxm[384];  // [0:192) x for 32 nodes, [192:384) mean1
  int t = threadIdx.x;
  int col = t & 127;
  int half = t >> 7;
  float wr[6], wn[6];
#pragma unroll
  for (int j = 0; j < 6; j++) {
    wr[j] = w_root[j * 128 + col];
    wn[j] = w_neigh[j * 128 + col];
  }
  float bb = b[col];
  for (int base = blockIdx.x * 32; base < N; base += gridDim.x * 32) {
    int cnt = min(32, N - base) * 6;
    __syncthreads();
    for (int i = t; i < 384; i += 256) {
      if (i < 192)
        sxm[i] = (i < cnt) ? x[(size_t)base * 6 + i] : 0.0f;
      else
        sxm[i] = (i - 192 < cnt) ? mean1[(size_t)base * 6 + (i - 192)] : 0.0f;
    }
    __syncthreads();
#pragma unroll
    for (int sub = 0; sub < 16; sub++) {
      int nl = sub * 2 + half;
      int n = base + nl;
      if (n < N) {
        float s = bb;
#pragma unroll
        for (int j = 0; j < 6; j++)
          s += sxm[nl * 6 + j] * wr[j] + sxm[192 + nl * 6 + j] * wn[j];
        cat2b[(size_t)n * 256 + col] = f2b(fmaxf(s, 0.0f));
      }
    }
  }
}

// ---- layer-2 mean aggregation: wave/node, 4x16 lanes, 8-deep prefetch ----
__global__ __launch_bounds__(256) void agg2_kernel(
    const u16* __restrict__ cat2b, u16* __restrict__ cat2w,
    const int* __restrict__ rowptr, const unsigned* __restrict__ src4, int N) {
  int n = blockIdx.x * 4 + (threadIdx.x >> 6);
  if (n >= N) return;
  int lane = threadIdx.x & 63;
  int g = lane >> 4;  // row group 0..3
  int c = lane & 15;  // col chunk (8 bf16)
  int beg = rowptr[n], end = rowptr[n + 1];
  f32x2 acc2[4];
#pragma unroll
  for (int j = 0; j < 4; j++) acc2[j] = (f32x2){0.f, 0.f};

  const int DEPTH = 8;
  int idx[DEPTH];
#pragma unroll
  for (int j = 0; j < DEPTH; j++) {
    int ii = beg + g + j * 4;
    idx[j] = (ii < end) ? (int)src4[ii] : -1;
  }
  uint4 u[DEPTH];
#pragma unroll
  for (int j = 0; j < DEPTH; j++) {
    int s = idx[j] < 0 ? 0 : idx[j];
    u[j] = *(const uint4*)(cat2b + (size_t)s * 256 + c * 8);
  }
#pragma unroll
  for (int j = 0; j < DEPTH; j++) {
    if (idx[j] >= 0) {
      acc2[0] += unpk2(u[j].x);
      acc2[1] += unpk2(u[j].y);
      acc2[2] += unpk2(u[j].z);
      acc2[3] += unpk2(u[j].w);
    }
  }
  for (int ii = beg + g + DEPTH * 4; ii < end; ii += 4) {
    uint4 uu = *(const uint4*)(cat2b + (size_t)src4[ii] * 256 + c * 8);
    acc2[0] += unpk2(uu.x);
    acc2[1] += unpk2(uu.y);
    acc2[2] += unpk2(uu.z);
    acc2[3] += unpk2(uu.w);
  }
#pragma unroll
  for (int j = 0; j < 4; j++) {
    acc2[j].x += __shfl_xor(acc2[j].x, 16, 64);
    acc2[j].y += __shfl_xor(acc2[j].y, 16, 64);
    acc2[j].x += __shfl_xor(acc2[j].x, 32, 64);
    acc2[j].y += __shfl_xor(acc2[j].y, 32, 64);
  }
  if (g == 0) {
    float inv = 1.0f / (float)max(end - beg, 1);
    uint4 ov;
    ov.x = packrn(acc2[0] * inv);
    ov.y = packrn(acc2[1] * inv);
    ov.z = packrn(acc2[2] * inv);
    ov.w = packrn(acc2[3] * inv);
    *(uint4*)(cat2w + (size_t)n * 256 + 128 + c * 8) = ov;
  }
}

// ---- bf16 MFMA GEMM: 512 thr, 8 waves, M-tile 128 (LDS-staged B) ----
template <int KT, int NT, bool RELU>
__global__ __launch_bounds__(512) void mfma_gemm(
    const u16* __restrict__ A, int lda, const u16* __restrict__ Bf,
    const float* __restrict__ bias, u16* __restrict__ C, int ldc, int M) {
  __shared__ u16 sB[KT * NT * 512];
  int tid = threadIdx.x;
  for (int i = tid; i < KT * NT * 64; i += 512)
    ((uint4*)sB)[i] = ((const uint4*)Bf)[i];
  int w = tid >> 6, l = tid & 63;
  int quad = l >> 4, col16 = l & 15;
  int rowA = blockIdx.x * 128 + w * 16 + col16;
  bool rv = rowA < M;
  const u16* ap = A + (size_t)rowA * lda + quad * 8;
  f32x4 acc[NT];
#pragma unroll
  for (int nt = 0; nt < NT; nt++) acc[nt] = (f32x4){0.f, 0.f, 0.f, 0.f};
  __syncthreads();
#pragma unroll
  for (int kt = 0; kt < KT; kt++) {
    bf16x8 av = {};
    if (rv) av = *(const bf16x8*)(ap + kt * 32);
#pragma unroll
    for (int nt = 0; nt < NT; nt++) {
      bf16x8 bv = *(const bf16x8*)(sB + ((kt * NT + nt) * 64 + l) * 8);
      acc[nt] = __builtin_amdgcn_mfma_f32_16x16x32_bf16(av, bv, acc[nt], 0, 0, 0);
    }
  }
  int rowbase = blockIdx.x * 128 + w * 16 + quad * 4;
#pragma unroll
  for (int r = 0; r < 4; r++) {
    int row = rowbase + r;
    if (row < M) {
#pragma unroll
      for (int nt = 0; nt < NT; nt++) {
        float v = acc[nt][r] + bias[nt * 16 + col16];
        if (RELU) v = fmaxf(v, 0.0f);
        C[(size_t)row * ldc + nt * 16 + col16] = f2b(v);
      }
    }
  }
}

// ---- barrier-free wave-local edge MLP: 16 edges/wave-tile, private sV ----
__global__ __launch_bounds__(256) void edge_mfma_kernel(
    const u16* __restrict__ Pcatb, const uint4* __restrict__ rec,
    const u16* __restrict__ W2f, const float* __restrict__ b_e2,
    const float* __restrict__ w_e3, const float* __restrict__ b_e3,
    const float* __restrict__ w_e1, float* __restrict__ out, int E) {
  __shared__ u16 sV[64 * 136];  // 4 wave-private slices [16][136]
  __shared__ u16 sW2[8192];

  int tid = threadIdx.x;
  int w = tid >> 6, l = tid & 63, quad = l >> 4, c16 = l & 15;
  int eg = l >> 4, ac = l & 15;  // wave-local phase-A mapping
  u16* sVw = sV + w * 16 * 136;

  for (int i = tid; i < 1024; i += 256)
    ((uint4*)sW2)[i] = ((const uint4*)W2f)[i];
  __syncthreads();  // only barrier: sW2 ready; loop below is barrier-free

  // wa2[j][p2]: rows j=0..3 of Wa, column pair p2 for this thread's 8 cols
  f32x2 wa2[4][4];
#pragma unroll
  for (int j = 0; j < 4; j++) {
    float4 w0 = *(const float4*)(w_e1 + (256 + j) * 128 + ac * 8);
    float4 w1 = *(const float4*)(w_e1 + (256 + j) * 128 + ac * 8 + 4);
    wa2[j][0] = (f32x2){w0.x, w0.y};
    wa2[j][1] = (f32x2){w0.z, w0.w};
    wa2[j][2] = (f32x2){w1.x, w1.y};
    wa2[j][3] = (f32x2){w1.z, w1.w};
  }
  float w3v[4], be2[4];
#pragma unroll
  for (int nt = 0; nt < 4; nt++) {
    w3v[nt] = w_e3[nt * 16 + c16];
    be2[nt] = b_e2[nt * 16 + c16];
  }
  float b3 = b_e3[0];

  int tiles = (E + 15) >> 4;      // 16-edge wave tiles
  int NW = gridDim.x * 4;         // wave-stream stride
  int t = blockIdx.x * 4 + w;

  uint4 rcA[4], rcB[4];  // rec double buffer (sequential, 2 tiles deep)
  uint4 ps[4];           // rolling ps buffer: refilled for t+NW during phase A

  auto load_rec = [&](int tt, uint4* rcv) {
#pragma unroll
    for (int it = 0; it < 4; it++) {
      int e = min(tt * 16 + it * 4 + eg, E - 1);
      rcv[it] = rec[e];
    }
  };

  // process wave-tile t: cur = rec(t), nxt = rec(t+NW); on exit cur = rec(t+2NW)
  auto process = [&](int t, uint4* cur, uint4* nxt) {
    bool hasnext = (t + NW < tiles);
    // pd block FIRST (oldest in vmcnt FIFO): dst-sorted -> cache-hot
    uint4 pdv[4];
#pragma unroll
    for (int it = 0; it < 4; it++) {
      int d = (int)(((cur[it].x >> 17) | (cur[it].y << 15)) & NMASK);
      pdv[it] = *(const uint4*)(Pcatb + (size_t)d * 256 + 128 + ac * 8);
    }
    // phase A: consume ps[it]/pdv[it], then refill ps[it] for tile t+NW
#pragma unroll
    for (int it = 0; it < 4; it++) {
      int e = it * 4 + eg;  // 0..15 local edge
      uint4 psu = ps[it], pdu = pdv[it];
      f32x2 a01 = unpk2(cur[it].z);
      f32x2 a23 = unpk2(cur[it].w);
      unsigned pu[4] = {psu.x, psu.y, psu.z, psu.w};
      unsigned du[4] = {pdu.x, pdu.y, pdu.z, pdu.w};
      uint4 ov;
      unsigned* op = (unsigned*)&ov;
#pragma unroll
      for (int p2 = 0; p2 < 4; p2++) {
        f32x2 f = unpk2(pu[p2]) + unpk2(du[p2]);
        f += a01.x * wa2[0][p2];
        f += a01.y * wa2[1][p2];
        f += a23.x * wa2[2][p2];
        f += a23.y * wa2[3][p2];
        f = __builtin_elementwise_max(f, (f32x2){0.f, 0.f});
        op[p2] = packrn(f);
      }
      *(uint4*)(sVw + e * 136 + ac * 8) = ov;
      if (ac == 0) *(unsigned*)(sVw + e * 136 + 128) = cur[it].y >> 2;
      if (hasnext) {
        int s = (int)(nxt[it].x & NMASK);
        ps[it] = *(const uint4*)(Pcatb + (size_t)s * 256 + ac * 8);
      }
    }
    // cur fully consumed -> reuse as rec(t+2NW) prefetch target
    if (t + 2 * NW < tiles) load_rec(t + 2 * NW, cur);
    // phase B: MFMA from own sV slice (same-wave write->read; compiler
    // inserts the lgkmcnt wait) + relu/w3 reduce + scatter out
    f32x4 acc[4];
#pragma unroll
    for (int nt = 0; nt < 4; nt++) acc[nt] = (f32x4){0.f, 0.f, 0.f, 0.f};
    const u16* vp = sVw + c16 * 136 + quad * 8;
#pragma unroll
    for (int kt = 0; kt < 4; kt++) {
      bf16x8 av = *(const bf16x8*)(vp + kt * 32);
#pragma unroll
      for (int nt = 0; nt < 4; nt++) {
        bf16x8 bv = *(const bf16x8*)(sW2 + ((kt * 4 + nt) * 64 + l) * 8);
        acc[nt] =
            __builtin_amdgcn_mfma_f32_16x16x32_bf16(av, bv, acc[nt], 0, 0, 0);
      }
    }
#pragma unroll
    for (int r = 0; r < 4; r++) {
      float p = 0.0f;
#pragma unroll
      for (int nt = 0; nt < 4; nt++)
        p += fmaxf(acc[nt][r] + be2[nt], 0.0f) * w3v[nt];
      p += __shfl_xor(p, 1, 64);
      p += __shfl_xor(p, 2, 64);
      p += __shfl_xor(p, 4, 64);
      p += __shfl_xor(p, 8, 64);
      if (c16 == 0) {
        int eloc = quad * 4 + r;  // 0..15 local edge
        if (t * 16 + eloc < E) {
          unsigned eid = *(const unsigned*)(sVw + eloc * 136 + 128);
          out[eid] = p + b3;
        }
      }
    }
  };

  if (t >= tiles) return;
  // prologue: rec 2-deep, ps for first tile (full latency once)
  load_rec(t, rcA);
#pragma unroll
  for (int it = 0; it < 4; it++) {
    int s = (int)(rcA[it].x & NMASK);
    ps[it] = *(const uint4*)(Pcatb + (size_t)s * 256 + ac * 8);
  }
  if (t + NW < tiles) load_rec(t + NW, rcB);

  while (t < tiles) {
    process(t, rcA, rcB);  // consumes ps(t), refills ps from rcB, rcA<-rec(t+2NW)
    t += NW;
    if (t >= tiles) break;
    process(t, rcB, rcA);
    t += NW;
  }
}

extern "C" void kernel_launch(void* const* d_in, const int* in_sizes, int n_in,
                              void* d_out, int out_size, void* d_ws,
                              size_t ws_size, hipStream_t stream) {
  const float* x        = (const float*)d_in[0];
  const int*   ei       = (const int*)d_in[1];
  const float* attr     = (const float*)d_in[2];
  const float* w1_root  = (const float*)d_in[3];
  const float* w1_neigh = (const float*)d_in[4];
  const float* b1       = (const float*)d_in[5];
  const float* w2_root  = (const float*)d_in[6];
  const float* w2_neigh = (const float*)d_in[7];
  const float* b2       = (const float*)d_in[8];
  const float* w_e1     = (const float*)d_in[9];
  const float* b_e1     = (const float*)d_in[10];
  const float* w_e2     = (const float*)d_in[11];
  const float* b_e2     = (const float*)d_in[12];
  const float* w_e3     = (const float*)d_in[13];
  const float* b_e3     = (const float*)d_in[14];
  float* out = (float*)d_out;

  int N = in_sizes[0] / 6;
  int E = in_sizes[2] / 4;
  int NBLK = (N + 255) / 256;

  int* wsi = (int*)d_ws;
  int*      rowptr  = wsi;                         // [N+1]
  int*      cursor  = wsi + 100004;                // [N]
  int*      partial = wsi + 200004;                // [512]
  unsigned* src4    = (unsigned*)(wsi + 200516);   // [E]
  uint4*    rec     = (uint4*)(wsi + 1800520);     // [E] x 16B
  float*    mean1   = (float*)(wsi + 8200520);     // [N,6]
  u16*      cat2b   = (u16*)(wsi + 8800520);       // [N,256] bf16
  float*    x32     = (float*)(wsi + 21600520);    // [N,8] f32 (aliases h2b;
                                                   //  dead before gemm1)
  u16*      h2b     = (u16*)(wsi + 21600520);      // [N,128] bf16
  u16*      B2f     = (u16*)(wsi + 28000520);      // 32768 u16
  u16*      WSDf    = (u16*)(wsi + 28016904);      // 32768 u16
  u16*      W2f     = (u16*)(wsi + 28033288);      // 8192 u16
  float*    pbias   = (float*)(wsi + 28037384);    // 256 f32

  (void)hipMemsetAsync(cursor, 0, (size_t)N * sizeof(int), stream);

  pack_weights<<<289, 256, 0, stream>>>(w2_root, w2_neigh, w_e1, w_e2, b_e1,
                                        B2f, WSDf, W2f, pbias);
  pack_x32<<<(N * 8 + 255) / 256, 256, 0, stream>>>(x, x32, N);

  // CSR build (by dst), attr packed into 16B records
  hist_kernel<<<(E + 255) / 256, 256, 0, stream>>>(ei, cursor, E);
  scan_block_sums<<<NBLK, 256, 0, stream>>>(cursor, partial, N);
  scan_partials<<<1, 512, 0, stream>>>(partial, rowptr, NBLK, E, N);
  scan_final<<<NBLK, 256, 0, stream>>>(partial, cursor, rowptr, N);
  scatter_rec<<<(E + 255) / 256, 256, 0, stream>>>(ei, attr, cursor, rec,
                                                   src4, E);

  // layer 1 (agg1 reads padded x32; fully consumed before gemm1 writes h2b)
  agg1_kernel<<<(N + 3) / 4, 256, 0, stream>>>(x32, rowptr, src4, mean1, N);
  dense1_kernel<<<1024, 256, 0, stream>>>(x, mean1, w1_root, w1_neigh, b1,
                                          cat2b, N);

  // layer 2 aggregation (8-deep pipelined bf16 gather)
  agg2_kernel<<<(N + 3) / 4, 256, 0, stream>>>(cat2b, cat2b, rowptr, src4, N);

  int gblocks = (N + 127) / 128;
  // h2 = relu([h1|mean2] @ [w2_root;w2_neigh] + b2)
  mfma_gemm<8, 8, true><<<gblocks, 512, 0, stream>>>(cat2b, 256, B2f, b2, h2b,
                                                     128, N);
  // Pcat = h2 @ [Ws|Wd] + [0|b_e1]
  mfma_gemm<4, 16, false><<<gblocks, 512, 0, stream>>>(h2b, 128, WSDf, pbias,
                                                       cat2b, 256, N);

  // barrier-free wave-local fused edge MLP
  edge_mfma_kernel<<<1024, 256, 0, stream>>>(cat2b, rec, W2f, b_e2, w_e3,
                                             b_e3, w_e1, out, E);
}